// Round 6
// baseline (2257.541 us; speedup 1.0000x reference)
//
#include <hip/hip_runtime.h>
#include <hip/hip_bf16.h>
#include <math.h>

#define BB 8
#define TT 4096
#define CC 512
#define BT (BB*TT)
#define KD 256
#define VD 512
#define NSUB 128
#define SUB 32

using bf16 = __hip_bfloat16;
typedef __attribute__((ext_vector_type(4))) float f32x4;
typedef __attribute__((ext_vector_type(8))) short s16x8;
typedef __attribute__((ext_vector_type(8))) unsigned short u16x8;
typedef const __attribute__((address_space(1))) unsigned int gu32;
typedef __attribute__((address_space(3))) unsigned int lu32;

static __device__ __forceinline__ float bf2f(bf16 x){ return __bfloat162float(x); }
static __device__ __forceinline__ bf16 f2bf(float x){ return __float2bfloat16(x); }
static __device__ __forceinline__ float bfbits(unsigned short u){
  union { unsigned int i; float f; } x; x.i = ((unsigned int)u)<<16; return x.f;
}
static __device__ __forceinline__ unsigned short f2bfbits(float f){
  union { bf16 b; unsigned short u; } x; x.b = f2bf(f); return x.u;
}
static __device__ __forceinline__ void gload16(const void* g, void* l){
  __builtin_amdgcn_global_load_lds((gu32*)g, (lu32*)l, 16, 0, 0);
}

// ---------------- workspace arena (bytes), peak ~217.3 MiB; Mseg lives in d_out ----------------
#define MiB 1048576ull
static constexpr size_t OFF_H1   = 0;           // bf16 BT*C (32)  ; p3 out GATED ; FFN RF
static constexpr size_t OFF_XX   = 32*MiB;      // bf16 BT*256 (16); dead by scan
static constexpr size_t OFF_DSEG = 32*MiB;      // f32 4096*64 (1) alias XX
static constexpr size_t OFF_HM   = 48*MiB;      // bf16 BT*C (32)  ; FFN HN
static constexpr size_t OFF_R    = 80*MiB;      // bf16 BT*256 (16); FFN KIN (spans R+K)
static constexpr size_t OFF_K    = 96*MiB;      // bf16 BT*256 (16)
static constexpr size_t OFF_V    = 112*MiB;     // bf16 BT*512 (32); FFN RIN
static constexpr size_t OFF_WD   = 144*MiB;     // f32 BT*256 (32) ; FFN KF low
static constexpr size_t OFF_G    = 176*MiB;     // bf16 BT*512 (32); FFN KF high
static constexpr size_t OFF_W1T  = 208*MiB;     // bf16 BT*64 (4)
static constexpr size_t WT_X1  = 212*MiB;            // 512x256 bf16
static constexpr size_t WT_R   = WT_X1  + 262144;
static constexpr size_t WT_K   = WT_R   + 262144;
static constexpr size_t WT_V   = WT_K   + 262144;
static constexpr size_t WT_G   = WT_V   + 524288;
static constexpr size_t WT_W1  = WT_G   + 524288;
static constexpr size_t WT_W2  = WT_W1  + 65536;
static constexpr size_t WT_O   = WT_W2  + 32768;
static constexpr size_t WT_KEY = WT_O   + 524288;
static constexpr size_t WT_REC = WT_KEY + 1048576;
static constexpr size_t WT_VAL = WT_REC + 524288;
static constexpr size_t WS_NEED = WT_VAL + 1048576;

// ---------------- fused weight convert+transpose for all 11 weights ----------------
__global__ void wconv_all(const float* s0, const float* s1, const float* s2, const float* s3,
                          const float* s4, const float* s5, const float* s6, const float* s7,
                          const float* s8, const float* s9, const float* s10, char* ws){
  struct E{int K,N,Npad; size_t off;};
  const E tab[11] = {
    {512,160,256,WT_X1},{512,256,256,WT_R},{512,256,256,WT_K},{512,512,512,WT_V},
    {512,512,512,WT_G},{512,64,64,WT_W1},{64,256,256,WT_W2},{512,512,512,WT_O},
    {512,1024,1024,WT_KEY},{512,512,512,WT_REC},{1024,512,512,WT_VAL}};
  const float* srcs[11] = {s0,s1,s2,s3,s4,s5,s6,s7,s8,s9,s10};
  int blk = blockIdx.x, i = 0, acc = 0;
  #pragma unroll 1
  for (; i<11; i++){ int nb = tab[i].K*tab[i].Npad/256; if (blk < acc+nb) break; acc += nb; }
  int idx = (blk-acc)*256 + threadIdx.x;
  int K = tab[i].K, N = tab[i].N;
  int n = idx / K, k = idx - n*K;
  float v = (n < N) ? srcs[i][(size_t)k*N + n] : 0.f;
  ((bf16*)(ws + tab[i].off))[idx] = f2bf(v);
}

// ---------------- LayerNorm over C=512, block per row, bf16 out ----------------
__global__ __launch_bounds__(256) void ln_bf16(const float* __restrict__ x, const float* __restrict__ w,
                                               const float* __restrict__ b, bf16* __restrict__ out){
  int bt = blockIdx.x;
  const float* row = x + (size_t)bt*CC;
  int t = threadIdx.x;
  float a0 = row[t], a1 = row[t+256];
  float s = a0 + a1, ss = a0*a0 + a1*a1;
  for (int off=32; off; off>>=1){ s += __shfl_down(s, off, 64); ss += __shfl_down(ss, off, 64); }
  __shared__ float ps[4], pss[4];
  int wv = t>>6, ln = t&63;
  if (ln==0){ ps[wv]=s; pss[wv]=ss; }
  __syncthreads();
  if (t==0){
    float S=ps[0]+ps[1]+ps[2]+ps[3], SS=pss[0]+pss[1]+pss[2]+pss[3];
    float mu = S/CC; float var = SS/CC - mu*mu;
    ps[0]=mu; pss[0]=rsqrtf(var+1e-5f);
  }
  __syncthreads();
  float mu = ps[0], inv = pss[0];
  out[(size_t)bt*CC + t]     = f2bf((a0-mu)*inv*w[t]+b[t]);
  out[(size_t)bt*CC + t+256] = f2bf((a1-mu)*inv*w[t+256]+b[t+256]);
}

// ---------------- xm = h + (shift(h)-h)*mu_x  (bf16 in/out) ----------------
__global__ void build_xm(const bf16* __restrict__ h, const float* __restrict__ mu_x, bf16* __restrict__ xm){
  size_t idx = (size_t)blockIdx.x*256 + threadIdx.x;
  int c = (int)(idx & (CC-1));
  size_t bt = idx >> 9;
  float hv = bf2f(h[idx]);
  float hp = (bt & (TT-1)) ? bf2f(h[idx - CC]) : 0.f;
  xm[idx] = f2bf(hv + (hp - hv)*mu_x[c]);
}

// ---------------- single lerp-mix build: hm = h + (hprev-h)*(xx_i @ W_x2[i] + bias_i) -------
__global__ __launch_bounds__(128) void build_hm(const bf16* __restrict__ h, const bf16* __restrict__ xx,
        const float* __restrict__ W_x2i, const float* __restrict__ x_biasi, bf16* __restrict__ hm){
  int bt0 = blockIdx.x*16;
  int c = blockIdx.y*128 + threadIdx.x;
  float W[32];
  #pragma unroll
  for (int r=0;r<32;r++) W[r] = W_x2i[(size_t)r*CC + c];
  float bia = x_biasi[c];
  #pragma unroll 1
  for (int j=0;j<16;j++){
    int bt = bt0+j;
    float hv = bf2f(h[(size_t)bt*CC + c]);
    float hp = ((bt & (TT-1)) != 0) ? bf2f(h[(size_t)(bt-1)*CC + c]) : 0.f;
    const bf16* xr = xx + (size_t)bt*256;
    float acc = bia;
    #pragma unroll
    for (int r=0;r<32;r++) acc += bf2f(xr[r])*W[r];
    hm[(size_t)bt*CC + c] = f2bf(hv + (hp-hv)*acc);
  }
}

// ---------------- epilogue modes ----------------
enum {EP_BF16, EP_TANH_BF16, EP_NEGEXP_F32, EP_RES_F32, EP_RELU2_BF16, EP_SIG_BF16, EP_FINAL_F32};

// ---------------- m97-style 128x128 MFMA GEMM with global_load_lds staging -------------
template<int MODE>
__global__ __launch_bounds__(256) void gemm128(
    const bf16* __restrict__ A, const bf16* __restrict__ Bt, void* __restrict__ Out,
    int N, int K, const float* __restrict__ auxf, const bf16* __restrict__ auxb)
{
  __shared__ bf16 Al[128][32];
  __shared__ bf16 Bl[128][32];
  int tid = threadIdx.x;
  int nbk = N>>7;
  int q8 = gridDim.x>>3;
  int o = (blockIdx.x & 7)*q8 + (blockIdx.x>>3);
  int nb = o % nbk, mb = o / nbk;
  int m0 = mb*128, n0 = nb*128;
  int wv = tid>>6, ln = tid&63;
  int wr = wv>>1, wc = wv&1;
  f32x4 acc[4][4];
  #pragma unroll
  for (int i=0;i<4;i++) for (int j=0;j<4;j++){ f32x4 z={0.f,0.f,0.f,0.f}; acc[i][j]=z; }
  int r0 = tid>>2, k0 = (tid&3)*8;
  const int nkt = K>>5;
  for (int kt=0; kt<nkt; kt++){
    const bf16* ga = A  + (size_t)(m0+r0)*K + kt*32 + k0;
    const bf16* gb = Bt + (size_t)(n0+r0)*K + kt*32 + k0;
    gload16(ga,                 (char*)&Al[0][0] + tid*16);
    gload16(ga + (size_t)64*K,  (char*)&Al[0][0] + (tid+256)*16);
    gload16(gb,                 (char*)&Bl[0][0] + tid*16);
    gload16(gb + (size_t)64*K,  (char*)&Bl[0][0] + (tid+256)*16);
    __syncthreads();
    int ks = (ln>>4)*8;
    s16x8 af[4], bq[4];
    #pragma unroll
    for (int i=0;i<4;i++){
      af[i] = *(const s16x8*)&Al[wr*64 + i*16 + (ln&15)][ks];
      bq[i] = *(const s16x8*)&Bl[wc*64 + i*16 + (ln&15)][ks];
    }
    #pragma unroll
    for (int mi=0;mi<4;mi++)
      #pragma unroll
      for (int ni=0;ni<4;ni++)
        acc[mi][ni] = __builtin_amdgcn_mfma_f32_16x16x32_bf16(af[mi], bq[ni], acc[mi][ni], 0,0,0);
    __syncthreads();
  }
  #pragma unroll
  for (int mi=0;mi<4;mi++)
    #pragma unroll
    for (int ni=0;ni<4;ni++){
      int col = n0 + wc*64 + ni*16 + (ln&15);
      int rb  = m0 + wr*64 + mi*16 + (ln>>4)*4;
      #pragma unroll
      for (int j=0;j<4;j++){
        size_t idx = (size_t)(rb+j)*N + col;
        float val = acc[mi][ni][j];
        if constexpr(MODE==EP_BF16)           ((bf16*)Out)[idx] = f2bf(val);
        else if constexpr(MODE==EP_TANH_BF16) ((bf16*)Out)[idx] = f2bf(tanhf(val));
        else if constexpr(MODE==EP_RES_F32)   ((float*)Out)[idx] = auxf[idx] + val;
        else if constexpr(MODE==EP_RELU2_BF16){ float m = fmaxf(val,0.f); ((bf16*)Out)[idx] = f2bf(m*m); }
        else if constexpr(MODE==EP_SIG_BF16)  ((bf16*)Out)[idx] = f2bf(1.f/(1.f+expf(-val)));
        else if constexpr(MODE==EP_FINAL_F32) ((float*)Out)[idx] = auxf[idx] + bf2f(auxb[idx])*val;
      }
    }
}

// ---------------- small-N GEMM (used for W1 N=64 and W2 K=64) -------------
template<int MODE>
__global__ __launch_bounds__(256) void gemm_bf16(
    const bf16* __restrict__ A, const bf16* __restrict__ Bt, void* __restrict__ Out,
    int N, int K, const float* __restrict__ auxf, const bf16* __restrict__ auxb,
    const float* __restrict__ bias)
{
  __shared__ bf16 Al[128][40];
  __shared__ bf16 Bl[64][40];
  int tid = threadIdx.x;
  int m0 = blockIdx.x*128, n0 = blockIdx.y*64;
  int wv = tid>>6, ln = tid&63;
  f32x4 acc[2][4];
  #pragma unroll
  for(int f=0;f<2;f++) for(int c=0;c<4;c++){ f32x4 z = {0.f,0.f,0.f,0.f}; acc[f][c]=z; }
  const int nkt = K>>5;
  for (int kt=0; kt<nkt; kt++){
    __syncthreads();
    {
      int c0 = tid, c1 = tid+256;
      int r = c0>>2, ko=(c0&3)*8;
      *(uint4*)&Al[r][ko] = *(const uint4*)&A[(size_t)(m0+r)*K + kt*32 + ko];
      r = c1>>2; ko=(c1&3)*8;
      *(uint4*)&Al[r][ko] = *(const uint4*)&A[(size_t)(m0+r)*K + kt*32 + ko];
      r = tid>>2; ko=(tid&3)*8;
      *(uint4*)&Bl[r][ko] = *(const uint4*)&Bt[(size_t)(n0+r)*K + kt*32 + ko];
    }
    __syncthreads();
    int ks = (ln>>4)*8;
    s16x8 af0 = *(const s16x8*)&Al[wv*32 + (ln&15)][ks];
    s16x8 af1 = *(const s16x8*)&Al[wv*32 + 16 + (ln&15)][ks];
    #pragma unroll
    for (int c=0;c<4;c++){
      s16x8 bfr = *(const s16x8*)&Bl[c*16 + (ln&15)][ks];
      acc[0][c] = __builtin_amdgcn_mfma_f32_16x16x32_bf16(af0, bfr, acc[0][c], 0,0,0);
      acc[1][c] = __builtin_amdgcn_mfma_f32_16x16x32_bf16(af1, bfr, acc[1][c], 0,0,0);
    }
  }
  #pragma unroll
  for (int f=0; f<2; f++) for (int c=0;c<4;c++){
    int col = n0 + c*16 + (ln&15);
    int rbase = m0 + wv*32 + f*16 + (ln>>4)*4;
    #pragma unroll
    for (int j=0;j<4;j++){
      size_t idx = (size_t)(rbase+j)*N + col;
      float val = acc[f][c][j];
      if constexpr(MODE==EP_TANH_BF16)      ((bf16*)Out)[idx] = f2bf(tanhf(val));
      else if constexpr(MODE==EP_NEGEXP_F32){ float w = -expf(val + bias[col]); ((float*)Out)[idx] = fmaxf(w, -20.f); }
    }
  }
}

// ---------------- WKV6 segment scan (32-token chunks, NSUB=128) ----------------
// P1: 2 waves/block; wave owns 64 v-cols; lane = k. State S[64] fits VGPRs.
__global__ __launch_bounds__(128,4) void wkv_p1(const bf16* __restrict__ kbuf, const bf16* __restrict__ vbuf,
      const float* __restrict__ wd, bf16* __restrict__ Mseg, float* __restrict__ Dseg){
  int bhs = blockIdx.x; int bh = bhs>>7, sub = bhs&127;
  int b = bh>>2, h = bh&3;
  int tid = threadIdx.x, wv = tid>>6, ln = tid&63;
  __shared__ float vtile[16][132];
  int t0 = sub*SUB;
  size_t kqbase = ((size_t)b*TT + t0)*KD + h*64 + ln;
  float csum = 0.f;
  float S[64];
  #pragma unroll
  for (int v=0;v<64;v++) S[v]=0.f;
  float wnxt = wd[kqbase];
  unsigned short qnxt = ((const unsigned short*)kbuf)[kqbase];
  #pragma unroll 1
  for (int tile=0; tile<2; tile++){
    int tb = t0 + tile*16;
    __syncthreads();
    {
      int t = tid>>3, c = (tid&7)*16;
      const unsigned short* vg = (const unsigned short*)vbuf + ((size_t)b*TT + tb + t)*VD + h*128 + c;
      u16x8 a8 = *(const u16x8*)vg;
      u16x8 b8 = *(const u16x8*)(vg+8);
      #pragma unroll
      for (int e=0;e<8;e++){ vtile[t][c+e] = bfbits(a8[e]); vtile[t][c+8+e] = bfbits(b8[e]); }
    }
    __syncthreads();
    #pragma unroll 1
    for (int tt=0;tt<16;tt++){
      int lt = tile*16+tt;
      float wcur = wnxt; unsigned short qcur = qnxt;
      if (lt < SUB-1){
        size_t gi = kqbase + (size_t)(lt+1)*KD;
        wnxt = wd[gi]; qnxt = ((const unsigned short*)kbuf)[gi];
      }
      csum += wcur;
      float e = expf(wcur), qv = bfbits(qcur);
      #pragma unroll
      for (int v4=0;v4<16;v4++){
        float4 vvv = *(const float4*)&vtile[tt][wv*64 + v4*4];
        S[v4*4+0] = e*S[v4*4+0] + qv*vvv.x;
        S[v4*4+1] = e*S[v4*4+1] + qv*vvv.y;
        S[v4*4+2] = e*S[v4*4+2] + qv*vvv.z;
        S[v4*4+3] = e*S[v4*4+3] + qv*vvv.w;
      }
    }
  }
  unsigned short* M = (unsigned short*)Mseg + (size_t)bhs*8192 + (size_t)ln*128 + wv*64;
  #pragma unroll
  for (int v4=0; v4<16; v4++){
    ushort4 s4;
    s4.x = f2bfbits(S[v4*4+0]); s4.y = f2bfbits(S[v4*4+1]);
    s4.z = f2bfbits(S[v4*4+2]); s4.w = f2bfbits(S[v4*4+3]);
    *(ushort4*)&M[v4*4] = s4;
  }
  if (wv==0) Dseg[(size_t)bhs*64 + ln] = expf(csum);
}

// P2: sequential combine across sub-chunks, IN-PLACE bf16 (Mseg becomes Sstart)
__global__ __launch_bounds__(256) void wkv_p2(bf16* __restrict__ MS, const float* __restrict__ Dseg){
  int idx = blockIdx.x*256 + threadIdx.x;
  int bh = idx>>13; int k = (idx>>7)&63; int v = idx&127;
  bf16* p = MS + (size_t)bh*NSUB*8192 + k*128 + v;
  const float* d = Dseg + (size_t)bh*NSUB*64 + k;
  float S = 0.f;
  float m = bf2f(p[0]); float D = d[0];
  #pragma unroll 1
  for (int seg=0; seg<NSUB; seg++){
    float mN=0.f, DN=0.f;
    if (seg < NSUB-1){ mN = bf2f(p[(size_t)(seg+1)*8192]); DN = d[(seg+1)*64]; }
    p[(size_t)seg*8192] = f2bf(S);
    S = D*S + m;
    m = mN; D = DN;
  }
}

// P3: v-lane layout. 128 threads = 128 v-channels; per-thread state S[64] (all k).
// e/q/r wave-uniform LDS reads; o lane-local; GN via 16-lane-group reduce. Fused GN+silu gate.
__global__ __launch_bounds__(128) void wkv_p3(const bf16* __restrict__ rbuf, const bf16* __restrict__ kbuf,
     const bf16* __restrict__ vbuf, const float* __restrict__ wd, const bf16* __restrict__ Sstart,
     const float* __restrict__ uu, const bf16* __restrict__ gg,
     const float* __restrict__ gn_w, const float* __restrict__ gn_b, bf16* __restrict__ gated){
  int bhs = blockIdx.x; int bh = bhs>>7, sub = bhs&127;
  int b = bh>>2, h = bh&3;
  int tid = threadIdx.x;
  __shared__ float ew[8][68], qk[8][68], rr[8][68], bu[8];
  __shared__ unsigned short vtb[8][128];
  __shared__ float ot[8][132];
  int tq = tid>>4, cq4 = (tid&15)*4, cq8 = (tid&15)*8;
  float4 u4 = *(const float4*)&uu[h*64 + cq4];
  // GN-phase per-thread constants: 8 channels starting at cq8
  float gw[8], gb[8];
  *(float4*)&gw[0] = *(const float4*)&gn_w[h*128+cq8];
  *(float4*)&gw[4] = *(const float4*)&gn_w[h*128+cq8+4];
  *(float4*)&gb[0] = *(const float4*)&gn_b[h*128+cq8];
  *(float4*)&gb[4] = *(const float4*)&gn_b[h*128+cq8+4];
  float S[64];
  const unsigned short* Sst = (const unsigned short*)Sstart + (size_t)bhs*8192;
  #pragma unroll
  for (int k=0;k<64;k++) S[k] = bfbits(Sst[k*128 + tid]);
  int t0 = sub*SUB;
  #pragma unroll 1
  for (int tile=0; tile<4; tile++){
    int tb = t0 + tile*8;
    // ---- stage 8 tokens of e/q/r/bu/v ----
    {
      float4 w4 = *(const float4*)&wd[((size_t)b*TT + tb + tq)*KD + h*64 + cq4];
      ew[tq][cq4+0]=expf(w4.x); ew[tq][cq4+1]=expf(w4.y); ew[tq][cq4+2]=expf(w4.z); ew[tq][cq4+3]=expf(w4.w);
      size_t gi = ((size_t)b*TT + tb + tq)*KD + h*64 + cq4;
      ushort4 k4 = *(const ushort4*)&((const unsigned short*)kbuf)[gi];
      ushort4 r4 = *(const ushort4*)&((const unsigned short*)rbuf)[gi];
      float q0=bfbits(k4.x),q1=bfbits(k4.y),q2=bfbits(k4.z),q3=bfbits(k4.w);
      float rv0=bfbits(r4.x),rv1=bfbits(r4.y),rv2=bfbits(r4.z),rv3=bfbits(r4.w);
      qk[tq][cq4+0]=q0; qk[tq][cq4+1]=q1; qk[tq][cq4+2]=q2; qk[tq][cq4+3]=q3;
      rr[tq][cq4+0]=rv0; rr[tq][cq4+1]=rv1; rr[tq][cq4+2]=rv2; rr[tq][cq4+3]=rv3;
      float part = rv0*q0*u4.x + rv1*q1*u4.y + rv2*q2*u4.z + rv3*q3*u4.w;
      part += __shfl_xor(part,1,64); part += __shfl_xor(part,2,64);
      part += __shfl_xor(part,4,64); part += __shfl_xor(part,8,64);
      if ((tid&15)==0) bu[tq] = part;
      *(u16x8*)&vtb[tq][cq8] = *(const u16x8*)&((const unsigned short*)vbuf)[((size_t)b*TT + tb + tq)*VD + h*128 + cq8];
    }
    __syncthreads();
    // ---- scan 8 tokens; o lane-local ----
    #pragma unroll 1
    for (int t=0;t<8;t++){
      float vl = bfbits(vtb[t][tid]);
      float o = 0.f;
      #pragma unroll 2
      for (int k4g=0;k4g<16;k4g++){
        float4 e4 = *(const float4*)&ew[t][k4g*4];
        float4 q4 = *(const float4*)&qk[t][k4g*4];
        float4 r4 = *(const float4*)&rr[t][k4g*4];
        int j = k4g*4;
        o += r4.x*S[j+0]; S[j+0] = e4.x*S[j+0] + q4.x*vl;
        o += r4.y*S[j+1]; S[j+1] = e4.y*S[j+1] + q4.y*vl;
        o += r4.z*S[j+2]; S[j+2] = e4.z*S[j+2] + q4.z*vl;
        o += r4.w*S[j+3]; S[j+3] = e4.w*S[j+3] + q4.w*vl;
      }
      o += bu[t]*vl;
      ot[t][tid] = o;
    }
    __syncthreads();
    // ---- GN + silu gate: thread handles token tq, channels cq8..cq8+7 ----
    {
      float o8[8];
      *(float4*)&o8[0] = *(const float4*)&ot[tq][cq8];
      *(float4*)&o8[4] = *(const float4*)&ot[tq][cq8+4];
      float s = 0.f, ss = 0.f;
      #pragma unroll
      for (int e=0;e<8;e++){ s += o8[e]; ss += o8[e]*o8[e]; }
      s += __shfl_xor(s,1,64); ss += __shfl_xor(ss,1,64);
      s += __shfl_xor(s,2,64); ss += __shfl_xor(ss,2,64);
      s += __shfl_xor(s,4,64); ss += __shfl_xor(ss,4,64);
      s += __shfl_xor(s,8,64); ss += __shfl_xor(ss,8,64);
      float mu = s*(1.f/128.f);
      float inv = rsqrtf(fmaxf(ss*(1.f/128.f) - mu*mu, 0.f) + 1e-5f);
      size_t go = ((size_t)b*TT + tb + tq)*VD + h*128 + cq8;
      u16x8 g8 = *(const u16x8*)&((const unsigned short*)gg)[go];
      u16x8 out8;
      #pragma unroll
      for (int e=0;e<8;e++){
        float xv = (o8[e]-mu)*inv*gw[e] + gb[e];
        float ga = bfbits(g8[e]);
        xv *= ga/(1.f+expf(-ga));
        out8[e] = f2bfbits(xv);
      }
      *(u16x8*)&((unsigned short*)gated)[go] = out8;
    }
  }
}

// ---------------- FFN lerp inputs (bf16 in/out) ----------------
__global__ void build_ffn_in(const bf16* __restrict__ hn, const float* __restrict__ mu_k,
                             const float* __restrict__ mu_r, bf16* __restrict__ kin, bf16* __restrict__ rin){
  size_t idx = (size_t)blockIdx.x*256 + threadIdx.x;
  int c = (int)(idx & (CC-1));
  size_t bt = idx >> 9;
  float hv = bf2f(hn[idx]);
  float hp = (bt & (TT-1)) ? bf2f(hn[idx - CC]) : 0.f;
  float d = hp - hv;
  kin[idx] = f2bf(hv + d*mu_k[c]);
  rin[idx] = f2bf(hv + d*mu_r[c]);
}

extern "C" void kernel_launch(void* const* d_in, const int* in_sizes, int n_in,
                              void* d_out, int out_size, void* d_ws, size_t ws_size,
                              hipStream_t stream){
  (void)in_sizes; (void)n_in; (void)out_size;
  if (ws_size < WS_NEED) return;
  const float* x      = (const float*)d_in[0];
  const float* ln1w   = (const float*)d_in[1];
  const float* ln1b   = (const float*)d_in[2];
  const float* mu_x   = (const float*)d_in[3];
  const float* W_x1   = (const float*)d_in[4];
  const float* W_x2   = (const float*)d_in[5];
  const float* x_bias = (const float*)d_in[6];
  const float* W_r    = (const float*)d_in[7];
  const float* W_k    = (const float*)d_in[8];
  const float* W_v    = (const float*)d_in[9];
  const float* W_g    = (const float*)d_in[10];
  const float* W_w1   = (const float*)d_in[11];
  const float* W_w2   = (const float*)d_in[12];
  const float* b_w2   = (const float*)d_in[13];
  const float* u      = (const float*)d_in[14];
  const float* gn_w   = (const float*)d_in[15];
  const float* gn_b   = (const float*)d_in[16];
  const float* W_o    = (const float*)d_in[17];
  const float* ln2w   = (const float*)d_in[18];
  const float* ln2b   = (const float*)d_in[19];
  const float* mu_k   = (const float*)d_in[20];
  const float* W_key  = (const float*)d_in[21];
  const float* mu_r   = (const float*)d_in[22];
  const float* W_rec  = (const float*)d_in[23];
  const float* W_val  = (const float*)d_in[24];
  char* ws = (char*)d_ws;
  auto F  = [&](size_t off){ return (float*)(ws+off); };
  auto Bf = [&](size_t off){ return (bf16*)(ws+off); };
  float* h2 = (float*)d_out;        // attn-out residual lives in d_out
  bf16* Mseg = (bf16*)d_out;        // scan summaries alias d_out (dead before O-gemm)

  // fused weight conversions (9920 blocks)
  wconv_all<<<9920,256,0,stream>>>(W_x1,W_r,W_k,W_v,W_g,W_w1,W_w2,W_o,W_key,W_rec,W_val, ws);

  // ---- attention pre-projections ----
  ln_bf16<<<BT,256,0,stream>>>(x, ln1w, ln1b, Bf(OFF_H1));
  build_xm<<<BT*CC/256,256,0,stream>>>(Bf(OFF_H1), mu_x, Bf(OFF_HM));
  gemm128<EP_TANH_BF16><<<512,256,0,stream>>>(Bf(OFF_HM), Bf(WT_X1), Bf(OFF_XX), 256,512, nullptr,nullptr);

  for (int i=0;i<5;i++){
    build_hm<<<dim3(BT/16,4),128,0,stream>>>(Bf(OFF_H1), Bf(OFF_XX)+i*32, W_x2 + (size_t)i*32*CC, x_bias + i*CC, Bf(OFF_HM));
    if (i==0)      gemm128<EP_BF16><<<512,256,0,stream>>>(Bf(OFF_HM), Bf(WT_R), Bf(OFF_R), 256,512, nullptr,nullptr);
    else if (i==1){
      gemm_bf16<EP_TANH_BF16><<<dim3(BT/128,1),256,0,stream>>>(Bf(OFF_HM), Bf(WT_W1), Bf(OFF_W1T), 64,512, nullptr,nullptr,nullptr);
      gemm_bf16<EP_NEGEXP_F32><<<dim3(BT/128,4),256,0,stream>>>(Bf(OFF_W1T), Bf(WT_W2), F(OFF_WD), 256,64, nullptr,nullptr,b_w2);
    }
    else if (i==2) gemm128<EP_BF16><<<512,256,0,stream>>>(Bf(OFF_HM), Bf(WT_K), Bf(OFF_K), 256,512, nullptr,nullptr);
    else if (i==3) gemm128<EP_BF16><<<1024,256,0,stream>>>(Bf(OFF_HM), Bf(WT_V), Bf(OFF_V), 512,512, nullptr,nullptr);
    else           gemm128<EP_BF16><<<1024,256,0,stream>>>(Bf(OFF_HM), Bf(WT_G), Bf(OFF_G), 512,512, nullptr,nullptr);
  }

  // ---- WKV6 segment scan (SUB=32, NSUB=128); Mseg/Sstart in d_out ----
  wkv_p1<<<BB*4*NSUB,128,0,stream>>>(Bf(OFF_K), Bf(OFF_V), F(OFF_WD), Mseg, F(OFF_DSEG));
  wkv_p2<<<BB*4*8192/256,256,0,stream>>>(Mseg, F(OFF_DSEG));
  wkv_p3<<<BB*4*NSUB,128,0,stream>>>(Bf(OFF_R), Bf(OFF_K), Bf(OFF_V), F(OFF_WD), Mseg, u,
                                     Bf(OFF_G), gn_w, gn_b, Bf(OFF_H1));

  // ---- output projection + residual -> h2 (in d_out; overwrites Mseg) ----
  gemm128<EP_RES_F32><<<1024,256,0,stream>>>(Bf(OFF_H1), Bf(WT_O), h2, 512,512, x,nullptr);

  // ---- channel mixing (FFN) ----
  ln_bf16<<<BT,256,0,stream>>>(h2, ln2w, ln2b, Bf(OFF_HM));
  build_ffn_in<<<BT*CC/256,256,0,stream>>>(Bf(OFF_HM), mu_k, mu_r, Bf(OFF_R), Bf(OFF_V));
  gemm128<EP_RELU2_BF16><<<2048,256,0,stream>>>(Bf(OFF_R), Bf(WT_KEY), Bf(OFF_WD), 1024,512, nullptr,nullptr);
  gemm128<EP_SIG_BF16><<<1024,256,0,stream>>>(Bf(OFF_V), Bf(WT_REC), Bf(OFF_H1), 512,512, nullptr,nullptr);
  gemm128<EP_FINAL_F32><<<1024,256,0,stream>>>(Bf(OFF_WD), Bf(WT_VAL), h2, 512,1024, h2, Bf(OFF_H1));
}

// Round 7
// 1044.362 us; speedup vs baseline: 2.1616x; 2.1616x over previous
//
#include <hip/hip_runtime.h>
#include <hip/hip_bf16.h>
#include <math.h>

#define BB 8
#define TT 4096
#define CC 512
#define BT (BB*TT)
#define KD 256
#define VD 512
#define NSUB 128
#define SUB 32

using bf16 = __hip_bfloat16;
typedef __attribute__((ext_vector_type(4))) float f32x4;
typedef __attribute__((ext_vector_type(8))) short s16x8;
typedef __attribute__((ext_vector_type(8))) unsigned short u16x8;
typedef const __attribute__((address_space(1))) unsigned int gu32;
typedef __attribute__((address_space(3))) unsigned int lu32;

static __device__ __forceinline__ float bf2f(bf16 x){ return __bfloat162float(x); }
static __device__ __forceinline__ bf16 f2bf(float x){ return __float2bfloat16(x); }
static __device__ __forceinline__ float bfbits(unsigned short u){
  union { unsigned int i; float f; } x; x.i = ((unsigned int)u)<<16; return x.f;
}
static __device__ __forceinline__ unsigned short f2bfbits(float f){
  union { bf16 b; unsigned short u; } x; x.b = f2bf(f); return x.u;
}
static __device__ __forceinline__ void gload16(const void* g, void* l){
  __builtin_amdgcn_global_load_lds((gu32*)g, (lu32*)l, 16, 0, 0);
}

// ---------------- workspace arena (bytes), peak ~217.3 MiB; Mseg lives in d_out ----------------
#define MiB 1048576ull
static constexpr size_t OFF_H1   = 0;           // bf16 BT*C (32)  ; p3 out GATED ; FFN RF
static constexpr size_t OFF_XX   = 32*MiB;      // bf16 BT*256 (16); dead by scan
static constexpr size_t OFF_DSEG = 32*MiB;      // f32 4096*64 (1) alias XX
static constexpr size_t OFF_HM   = 48*MiB;      // bf16 BT*C (32)  ; FFN HN
static constexpr size_t OFF_R    = 80*MiB;      // bf16 BT*256 (16); FFN KIN (spans R+K)
static constexpr size_t OFF_K    = 96*MiB;      // bf16 BT*256 (16)
static constexpr size_t OFF_V    = 112*MiB;     // bf16 BT*512 (32); FFN RIN
static constexpr size_t OFF_WD   = 144*MiB;     // f32 BT*256 (32) ; FFN KF low
static constexpr size_t OFF_G    = 176*MiB;     // bf16 BT*512 (32); FFN KF high
static constexpr size_t OFF_W1T  = 208*MiB;     // bf16 BT*64 (4)
static constexpr size_t WT_X1  = 212*MiB;            // 512x256 bf16
static constexpr size_t WT_R   = WT_X1  + 262144;
static constexpr size_t WT_K   = WT_R   + 262144;
static constexpr size_t WT_V   = WT_K   + 262144;
static constexpr size_t WT_G   = WT_V   + 524288;
static constexpr size_t WT_W1  = WT_G   + 524288;
static constexpr size_t WT_W2  = WT_W1  + 65536;
static constexpr size_t WT_O   = WT_W2  + 32768;
static constexpr size_t WT_KEY = WT_O   + 524288;
static constexpr size_t WT_REC = WT_KEY + 1048576;
static constexpr size_t WT_VAL = WT_REC + 524288;
static constexpr size_t WS_NEED = WT_VAL + 1048576;

// ---------------- fused weight convert+transpose for all 11 weights ----------------
__global__ void wconv_all(const float* s0, const float* s1, const float* s2, const float* s3,
                          const float* s4, const float* s5, const float* s6, const float* s7,
                          const float* s8, const float* s9, const float* s10, char* ws){
  struct E{int K,N,Npad; size_t off;};
  const E tab[11] = {
    {512,160,256,WT_X1},{512,256,256,WT_R},{512,256,256,WT_K},{512,512,512,WT_V},
    {512,512,512,WT_G},{512,64,64,WT_W1},{64,256,256,WT_W2},{512,512,512,WT_O},
    {512,1024,1024,WT_KEY},{512,512,512,WT_REC},{1024,512,512,WT_VAL}};
  const float* srcs[11] = {s0,s1,s2,s3,s4,s5,s6,s7,s8,s9,s10};
  int blk = blockIdx.x, i = 0, acc = 0;
  #pragma unroll 1
  for (; i<11; i++){ int nb = tab[i].K*tab[i].Npad/256; if (blk < acc+nb) break; acc += nb; }
  int idx = (blk-acc)*256 + threadIdx.x;
  int K = tab[i].K, N = tab[i].N;
  int n = idx / K, k = idx - n*K;
  float v = (n < N) ? srcs[i][(size_t)k*N + n] : 0.f;
  ((bf16*)(ws + tab[i].off))[idx] = f2bf(v);
}

// ---------------- LayerNorm over C=512, block per row, bf16 out ----------------
__global__ __launch_bounds__(256) void ln_bf16(const float* __restrict__ x, const float* __restrict__ w,
                                               const float* __restrict__ b, bf16* __restrict__ out){
  int bt = blockIdx.x;
  const float* row = x + (size_t)bt*CC;
  int t = threadIdx.x;
  float a0 = row[t], a1 = row[t+256];
  float s = a0 + a1, ss = a0*a0 + a1*a1;
  for (int off=32; off; off>>=1){ s += __shfl_down(s, off, 64); ss += __shfl_down(ss, off, 64); }
  __shared__ float ps[4], pss[4];
  int wv = t>>6, ln = t&63;
  if (ln==0){ ps[wv]=s; pss[wv]=ss; }
  __syncthreads();
  if (t==0){
    float S=ps[0]+ps[1]+ps[2]+ps[3], SS=pss[0]+pss[1]+pss[2]+pss[3];
    float mu = S/CC; float var = SS/CC - mu*mu;
    ps[0]=mu; pss[0]=rsqrtf(var+1e-5f);
  }
  __syncthreads();
  float mu = ps[0], inv = pss[0];
  out[(size_t)bt*CC + t]     = f2bf((a0-mu)*inv*w[t]+b[t]);
  out[(size_t)bt*CC + t+256] = f2bf((a1-mu)*inv*w[t+256]+b[t+256]);
}

// ---------------- xm = h + (shift(h)-h)*mu_x  (bf16 in/out) ----------------
__global__ void build_xm(const bf16* __restrict__ h, const float* __restrict__ mu_x, bf16* __restrict__ xm){
  size_t idx = (size_t)blockIdx.x*256 + threadIdx.x;
  int c = (int)(idx & (CC-1));
  size_t bt = idx >> 9;
  float hv = bf2f(h[idx]);
  float hp = (bt & (TT-1)) ? bf2f(h[idx - CC]) : 0.f;
  xm[idx] = f2bf(hv + (hp - hv)*mu_x[c]);
}

// ---------------- single lerp-mix build: hm = h + (hprev-h)*(xx_i @ W_x2[i] + bias_i) -------
__global__ __launch_bounds__(128) void build_hm(const bf16* __restrict__ h, const bf16* __restrict__ xx,
        const float* __restrict__ W_x2i, const float* __restrict__ x_biasi, bf16* __restrict__ hm){
  int bt0 = blockIdx.x*16;
  int c = blockIdx.y*128 + threadIdx.x;
  float W[32];
  #pragma unroll
  for (int r=0;r<32;r++) W[r] = W_x2i[(size_t)r*CC + c];
  float bia = x_biasi[c];
  #pragma unroll 1
  for (int j=0;j<16;j++){
    int bt = bt0+j;
    float hv = bf2f(h[(size_t)bt*CC + c]);
    float hp = ((bt & (TT-1)) != 0) ? bf2f(h[(size_t)(bt-1)*CC + c]) : 0.f;
    const bf16* xr = xx + (size_t)bt*256;
    float acc = bia;
    #pragma unroll
    for (int r=0;r<32;r++) acc += bf2f(xr[r])*W[r];
    hm[(size_t)bt*CC + c] = f2bf(hv + (hp-hv)*acc);
  }
}

// ---------------- epilogue modes ----------------
enum {EP_BF16, EP_TANH_BF16, EP_NEGEXP_F32, EP_RES_F32, EP_RELU2_BF16, EP_SIG_BF16, EP_FINAL_F32};

// ---------------- m97-style 128x128 MFMA GEMM with global_load_lds staging -------------
template<int MODE>
__global__ __launch_bounds__(256) void gemm128(
    const bf16* __restrict__ A, const bf16* __restrict__ Bt, void* __restrict__ Out,
    int N, int K, const float* __restrict__ auxf, const bf16* __restrict__ auxb)
{
  __shared__ bf16 Al[128][32];
  __shared__ bf16 Bl[128][32];
  int tid = threadIdx.x;
  int nbk = N>>7;
  int q8 = gridDim.x>>3;
  int o = (blockIdx.x & 7)*q8 + (blockIdx.x>>3);
  int nb = o % nbk, mb = o / nbk;
  int m0 = mb*128, n0 = nb*128;
  int wv = tid>>6, ln = tid&63;
  int wr = wv>>1, wc = wv&1;
  f32x4 acc[4][4];
  #pragma unroll
  for (int i=0;i<4;i++) for (int j=0;j<4;j++){ f32x4 z={0.f,0.f,0.f,0.f}; acc[i][j]=z; }
  int r0 = tid>>2, k0 = (tid&3)*8;
  const int nkt = K>>5;
  for (int kt=0; kt<nkt; kt++){
    const bf16* ga = A  + (size_t)(m0+r0)*K + kt*32 + k0;
    const bf16* gb = Bt + (size_t)(n0+r0)*K + kt*32 + k0;
    gload16(ga,                 (char*)&Al[0][0] + tid*16);
    gload16(ga + (size_t)64*K,  (char*)&Al[0][0] + (tid+256)*16);
    gload16(gb,                 (char*)&Bl[0][0] + tid*16);
    gload16(gb + (size_t)64*K,  (char*)&Bl[0][0] + (tid+256)*16);
    __syncthreads();
    int ks = (ln>>4)*8;
    s16x8 af[4], bq[4];
    #pragma unroll
    for (int i=0;i<4;i++){
      af[i] = *(const s16x8*)&Al[wr*64 + i*16 + (ln&15)][ks];
      bq[i] = *(const s16x8*)&Bl[wc*64 + i*16 + (ln&15)][ks];
    }
    #pragma unroll
    for (int mi=0;mi<4;mi++)
      #pragma unroll
      for (int ni=0;ni<4;ni++)
        acc[mi][ni] = __builtin_amdgcn_mfma_f32_16x16x32_bf16(af[mi], bq[ni], acc[mi][ni], 0,0,0);
    __syncthreads();
  }
  #pragma unroll
  for (int mi=0;mi<4;mi++)
    #pragma unroll
    for (int ni=0;ni<4;ni++){
      int col = n0 + wc*64 + ni*16 + (ln&15);
      int rb  = m0 + wr*64 + mi*16 + (ln>>4)*4;
      #pragma unroll
      for (int j=0;j<4;j++){
        size_t idx = (size_t)(rb+j)*N + col;
        float val = acc[mi][ni][j];
        if constexpr(MODE==EP_BF16)           ((bf16*)Out)[idx] = f2bf(val);
        else if constexpr(MODE==EP_TANH_BF16) ((bf16*)Out)[idx] = f2bf(tanhf(val));
        else if constexpr(MODE==EP_RES_F32)   ((float*)Out)[idx] = auxf[idx] + val;
        else if constexpr(MODE==EP_RELU2_BF16){ float m = fmaxf(val,0.f); ((bf16*)Out)[idx] = f2bf(m*m); }
        else if constexpr(MODE==EP_SIG_BF16)  ((bf16*)Out)[idx] = f2bf(1.f/(1.f+expf(-val)));
        else if constexpr(MODE==EP_FINAL_F32) ((float*)Out)[idx] = auxf[idx] + bf2f(auxb[idx])*val;
      }
    }
}

// ---------------- small-N GEMM (used for W1 N=64 and W2 K=64) -------------
template<int MODE>
__global__ __launch_bounds__(256) void gemm_bf16(
    const bf16* __restrict__ A, const bf16* __restrict__ Bt, void* __restrict__ Out,
    int N, int K, const float* __restrict__ auxf, const bf16* __restrict__ auxb,
    const float* __restrict__ bias)
{
  __shared__ bf16 Al[128][40];
  __shared__ bf16 Bl[64][40];
  int tid = threadIdx.x;
  int m0 = blockIdx.x*128, n0 = blockIdx.y*64;
  int wv = tid>>6, ln = tid&63;
  f32x4 acc[2][4];
  #pragma unroll
  for(int f=0;f<2;f++) for(int c=0;c<4;c++){ f32x4 z = {0.f,0.f,0.f,0.f}; acc[f][c]=z; }
  const int nkt = K>>5;
  for (int kt=0; kt<nkt; kt++){
    __syncthreads();
    {
      int c0 = tid, c1 = tid+256;
      int r = c0>>2, ko=(c0&3)*8;
      *(uint4*)&Al[r][ko] = *(const uint4*)&A[(size_t)(m0+r)*K + kt*32 + ko];
      r = c1>>2; ko=(c1&3)*8;
      *(uint4*)&Al[r][ko] = *(const uint4*)&A[(size_t)(m0+r)*K + kt*32 + ko];
      r = tid>>2; ko=(tid&3)*8;
      *(uint4*)&Bl[r][ko] = *(const uint4*)&Bt[(size_t)(n0+r)*K + kt*32 + ko];
    }
    __syncthreads();
    int ks = (ln>>4)*8;
    s16x8 af0 = *(const s16x8*)&Al[wv*32 + (ln&15)][ks];
    s16x8 af1 = *(const s16x8*)&Al[wv*32 + 16 + (ln&15)][ks];
    #pragma unroll
    for (int c=0;c<4;c++){
      s16x8 bfr = *(const s16x8*)&Bl[c*16 + (ln&15)][ks];
      acc[0][c] = __builtin_amdgcn_mfma_f32_16x16x32_bf16(af0, bfr, acc[0][c], 0,0,0);
      acc[1][c] = __builtin_amdgcn_mfma_f32_16x16x32_bf16(af1, bfr, acc[1][c], 0,0,0);
    }
  }
  #pragma unroll
  for (int f=0; f<2; f++) for (int c=0;c<4;c++){
    int col = n0 + c*16 + (ln&15);
    int rbase = m0 + wv*32 + f*16 + (ln>>4)*4;
    #pragma unroll
    for (int j=0;j<4;j++){
      size_t idx = (size_t)(rbase+j)*N + col;
      float val = acc[f][c][j];
      if constexpr(MODE==EP_TANH_BF16)      ((bf16*)Out)[idx] = f2bf(tanhf(val));
      else if constexpr(MODE==EP_NEGEXP_F32){ float w = -expf(val + bias[col]); ((float*)Out)[idx] = fmaxf(w, -20.f); }
    }
  }
}

// ---------------- WKV6 segment scan (32-token chunks, NSUB=128) ----------------
// P1: 2 waves/block; wave owns 64 v-cols; lane = k. State S[64] fits VGPRs.
__global__ __launch_bounds__(128,4) void wkv_p1(const bf16* __restrict__ kbuf, const bf16* __restrict__ vbuf,
      const float* __restrict__ wd, bf16* __restrict__ Mseg, float* __restrict__ Dseg){
  int bhs = blockIdx.x; int bh = bhs>>7, sub = bhs&127;
  int b = bh>>2, h = bh&3;
  int tid = threadIdx.x, wv = tid>>6, ln = tid&63;
  __shared__ float vtile[16][132];
  int t0 = sub*SUB;
  size_t kqbase = ((size_t)b*TT + t0)*KD + h*64 + ln;
  float csum = 0.f;
  float S[64];
  #pragma unroll
  for (int v=0;v<64;v++) S[v]=0.f;
  float wnxt = wd[kqbase];
  unsigned short qnxt = ((const unsigned short*)kbuf)[kqbase];
  #pragma unroll 1
  for (int tile=0; tile<2; tile++){
    int tb = t0 + tile*16;
    __syncthreads();
    {
      int t = tid>>3, c = (tid&7)*16;
      const unsigned short* vg = (const unsigned short*)vbuf + ((size_t)b*TT + tb + t)*VD + h*128 + c;
      u16x8 a8 = *(const u16x8*)vg;
      u16x8 b8 = *(const u16x8*)(vg+8);
      #pragma unroll
      for (int e=0;e<8;e++){ vtile[t][c+e] = bfbits(a8[e]); vtile[t][c+8+e] = bfbits(b8[e]); }
    }
    __syncthreads();
    #pragma unroll 1
    for (int tt=0;tt<16;tt++){
      int lt = tile*16+tt;
      float wcur = wnxt; unsigned short qcur = qnxt;
      if (lt < SUB-1){
        size_t gi = kqbase + (size_t)(lt+1)*KD;
        wnxt = wd[gi]; qnxt = ((const unsigned short*)kbuf)[gi];
      }
      csum += wcur;
      float e = expf(wcur), qv = bfbits(qcur);
      #pragma unroll
      for (int v4=0;v4<16;v4++){
        float4 vvv = *(const float4*)&vtile[tt][wv*64 + v4*4];
        S[v4*4+0] = e*S[v4*4+0] + qv*vvv.x;
        S[v4*4+1] = e*S[v4*4+1] + qv*vvv.y;
        S[v4*4+2] = e*S[v4*4+2] + qv*vvv.z;
        S[v4*4+3] = e*S[v4*4+3] + qv*vvv.w;
      }
    }
  }
  unsigned short* M = (unsigned short*)Mseg + (size_t)bhs*8192 + (size_t)ln*128 + wv*64;
  #pragma unroll
  for (int v4=0; v4<16; v4++){
    ushort4 s4;
    s4.x = f2bfbits(S[v4*4+0]); s4.y = f2bfbits(S[v4*4+1]);
    s4.z = f2bfbits(S[v4*4+2]); s4.w = f2bfbits(S[v4*4+3]);
    *(ushort4*)&M[v4*4] = s4;
  }
  if (wv==0) Dseg[(size_t)bhs*64 + ln] = expf(csum);
}

// P2: sequential combine across sub-chunks, IN-PLACE bf16 (Mseg becomes Sstart)
__global__ __launch_bounds__(256) void wkv_p2(bf16* __restrict__ MS, const float* __restrict__ Dseg){
  int idx = blockIdx.x*256 + threadIdx.x;
  int bh = idx>>13; int k = (idx>>7)&63; int v = idx&127;
  bf16* p = MS + (size_t)bh*NSUB*8192 + k*128 + v;
  const float* d = Dseg + (size_t)bh*NSUB*64 + k;
  float S = 0.f;
  float m = bf2f(p[0]); float D = d[0];
  #pragma unroll 1
  for (int seg=0; seg<NSUB; seg++){
    float mN=0.f, DN=0.f;
    if (seg < NSUB-1){ mN = bf2f(p[(size_t)(seg+1)*8192]); DN = d[(seg+1)*64]; }
    p[(size_t)seg*8192] = f2bf(S);
    S = D*S + m;
    m = mN; D = DN;
  }
}

// P3: v-lane layout, FULLY-UNROLLED k loop (compile-time reg indices — rule #20).
// 128 threads = 128 v-channels; per-thread state S[64]; GN via 16-lane-group reduce.
__global__ __launch_bounds__(128) void wkv_p3(const bf16* __restrict__ rbuf, const bf16* __restrict__ kbuf,
     const bf16* __restrict__ vbuf, const float* __restrict__ wd, const bf16* __restrict__ Sstart,
     const float* __restrict__ uu, const bf16* __restrict__ gg,
     const float* __restrict__ gn_w, const float* __restrict__ gn_b, bf16* __restrict__ gated){
  int bhs = blockIdx.x; int bh = bhs>>7, sub = bhs&127;
  int b = bh>>2, h = bh&3;
  int tid = threadIdx.x;
  __shared__ float ew[8][68], qk[8][68], rr[8][68], bu[8];
  __shared__ unsigned short vtb[8][128];
  __shared__ float ot[8][132];
  int tq = tid>>4, cq4 = (tid&15)*4, cq8 = (tid&15)*8;
  float4 u4 = *(const float4*)&uu[h*64 + cq4];
  float gw[8], gb[8];
  *(float4*)&gw[0] = *(const float4*)&gn_w[h*128+cq8];
  *(float4*)&gw[4] = *(const float4*)&gn_w[h*128+cq8+4];
  *(float4*)&gb[0] = *(const float4*)&gn_b[h*128+cq8];
  *(float4*)&gb[4] = *(const float4*)&gn_b[h*128+cq8+4];
  float S[64];
  const unsigned short* Sst = (const unsigned short*)Sstart + (size_t)bhs*8192;
  #pragma unroll
  for (int k=0;k<64;k++) S[k] = bfbits(Sst[k*128 + tid]);
  int t0 = sub*SUB;
  #pragma unroll 1
  for (int tile=0; tile<4; tile++){
    int tb = t0 + tile*8;
    // ---- stage 8 tokens of e/q/r/bu/v ----
    {
      float4 w4 = *(const float4*)&wd[((size_t)b*TT + tb + tq)*KD + h*64 + cq4];
      ew[tq][cq4+0]=expf(w4.x); ew[tq][cq4+1]=expf(w4.y); ew[tq][cq4+2]=expf(w4.z); ew[tq][cq4+3]=expf(w4.w);
      size_t gi = ((size_t)b*TT + tb + tq)*KD + h*64 + cq4;
      ushort4 k4 = *(const ushort4*)&((const unsigned short*)kbuf)[gi];
      ushort4 r4 = *(const ushort4*)&((const unsigned short*)rbuf)[gi];
      float q0=bfbits(k4.x),q1=bfbits(k4.y),q2=bfbits(k4.z),q3=bfbits(k4.w);
      float rv0=bfbits(r4.x),rv1=bfbits(r4.y),rv2=bfbits(r4.z),rv3=bfbits(r4.w);
      qk[tq][cq4+0]=q0; qk[tq][cq4+1]=q1; qk[tq][cq4+2]=q2; qk[tq][cq4+3]=q3;
      rr[tq][cq4+0]=rv0; rr[tq][cq4+1]=rv1; rr[tq][cq4+2]=rv2; rr[tq][cq4+3]=rv3;
      float part = rv0*q0*u4.x + rv1*q1*u4.y + rv2*q2*u4.z + rv3*q3*u4.w;
      part += __shfl_xor(part,1,64); part += __shfl_xor(part,2,64);
      part += __shfl_xor(part,4,64); part += __shfl_xor(part,8,64);
      if ((tid&15)==0) bu[tq] = part;
      *(u16x8*)&vtb[tq][cq8] = *(const u16x8*)&((const unsigned short*)vbuf)[((size_t)b*TT + tb + tq)*VD + h*128 + cq8];
    }
    __syncthreads();
    // ---- scan 8 tokens; o lane-local; k loop FULLY unrolled ----
    #pragma unroll 1
    for (int t=0;t<8;t++){
      float vl = bfbits(vtb[t][tid]);
      float o = 0.f;
      #pragma unroll
      for (int k4g=0;k4g<16;k4g++){
        float4 e4 = *(const float4*)&ew[t][k4g*4];
        float4 q4 = *(const float4*)&qk[t][k4g*4];
        float4 r4 = *(const float4*)&rr[t][k4g*4];
        int j = k4g*4;
        o += r4.x*S[j+0]; S[j+0] = e4.x*S[j+0] + q4.x*vl;
        o += r4.y*S[j+1]; S[j+1] = e4.y*S[j+1] + q4.y*vl;
        o += r4.z*S[j+2]; S[j+2] = e4.z*S[j+2] + q4.z*vl;
        o += r4.w*S[j+3]; S[j+3] = e4.w*S[j+3] + q4.w*vl;
      }
      o += bu[t]*vl;
      ot[t][tid] = o;
    }
    __syncthreads();
    // ---- GN + silu gate: thread handles token tq, channels cq8..cq8+7 ----
    {
      float o8[8];
      *(float4*)&o8[0] = *(const float4*)&ot[tq][cq8];
      *(float4*)&o8[4] = *(const float4*)&ot[tq][cq8+4];
      float s = 0.f, ss = 0.f;
      #pragma unroll
      for (int e=0;e<8;e++){ s += o8[e]; ss += o8[e]*o8[e]; }
      s += __shfl_xor(s,1,64); ss += __shfl_xor(ss,1,64);
      s += __shfl_xor(s,2,64); ss += __shfl_xor(ss,2,64);
      s += __shfl_xor(s,4,64); ss += __shfl_xor(ss,4,64);
      s += __shfl_xor(s,8,64); ss += __shfl_xor(ss,8,64);
      float mu = s*(1.f/128.f);
      float inv = rsqrtf(fmaxf(ss*(1.f/128.f) - mu*mu, 0.f) + 1e-5f);
      size_t go = ((size_t)b*TT + tb + tq)*VD + h*128 + cq8;
      u16x8 g8 = *(const u16x8*)&((const unsigned short*)gg)[go];
      u16x8 out8;
      #pragma unroll
      for (int e=0;e<8;e++){
        float xv = (o8[e]-mu)*inv*gw[e] + gb[e];
        float ga = bfbits(g8[e]);
        xv *= ga/(1.f+expf(-ga));
        out8[e] = f2bfbits(xv);
      }
      *(u16x8*)&((unsigned short*)gated)[go] = out8;
    }
    __syncthreads();
  }
}

// ---------------- FFN lerp inputs (bf16 in/out) ----------------
__global__ void build_ffn_in(const bf16* __restrict__ hn, const float* __restrict__ mu_k,
                             const float* __restrict__ mu_r, bf16* __restrict__ kin, bf16* __restrict__ rin){
  size_t idx = (size_t)blockIdx.x*256 + threadIdx.x;
  int c = (int)(idx & (CC-1));
  size_t bt = idx >> 9;
  float hv = bf2f(hn[idx]);
  float hp = (bt & (TT-1)) ? bf2f(hn[idx - CC]) : 0.f;
  float d = hp - hv;
  kin[idx] = f2bf(hv + d*mu_k[c]);
  rin[idx] = f2bf(hv + d*mu_r[c]);
}

extern "C" void kernel_launch(void* const* d_in, const int* in_sizes, int n_in,
                              void* d_out, int out_size, void* d_ws, size_t ws_size,
                              hipStream_t stream){
  (void)in_sizes; (void)n_in; (void)out_size;
  if (ws_size < WS_NEED) return;
  const float* x      = (const float*)d_in[0];
  const float* ln1w   = (const float*)d_in[1];
  const float* ln1b   = (const float*)d_in[2];
  const float* mu_x   = (const float*)d_in[3];
  const float* W_x1   = (const float*)d_in[4];
  const float* W_x2   = (const float*)d_in[5];
  const float* x_bias = (const float*)d_in[6];
  const float* W_r    = (const float*)d_in[7];
  const float* W_k    = (const float*)d_in[8];
  const float* W_v    = (const float*)d_in[9];
  const float* W_g    = (const float*)d_in[10];
  const float* W_w1   = (const float*)d_in[11];
  const float* W_w2   = (const float*)d_in[12];
  const float* b_w2   = (const float*)d_in[13];
  const float* u      = (const float*)d_in[14];
  const float* gn_w   = (const float*)d_in[15];
  const float* gn_b   = (const float*)d_in[16];
  const float* W_o    = (const float*)d_in[17];
  const float* ln2w   = (const float*)d_in[18];
  const float* ln2b   = (const float*)d_in[19];
  const float* mu_k   = (const float*)d_in[20];
  const float* W_key  = (const float*)d_in[21];
  const float* mu_r   = (const float*)d_in[22];
  const float* W_rec  = (const float*)d_in[23];
  const float* W_val  = (const float*)d_in[24];
  char* ws = (char*)d_ws;
  auto F  = [&](size_t off){ return (float*)(ws+off); };
  auto Bf = [&](size_t off){ return (bf16*)(ws+off); };
  float* h2 = (float*)d_out;        // attn-out residual lives in d_out
  bf16* Mseg = (bf16*)d_out;        // scan summaries alias d_out (dead before O-gemm)

  // fused weight conversions (9920 blocks)
  wconv_all<<<9920,256,0,stream>>>(W_x1,W_r,W_k,W_v,W_g,W_w1,W_w2,W_o,W_key,W_rec,W_val, ws);

  // ---- attention pre-projections ----
  ln_bf16<<<BT,256,0,stream>>>(x, ln1w, ln1b, Bf(OFF_H1));
  build_xm<<<BT*CC/256,256,0,stream>>>(Bf(OFF_H1), mu_x, Bf(OFF_HM));
  gemm128<EP_TANH_BF16><<<512,256,0,stream>>>(Bf(OFF_HM), Bf(WT_X1), Bf(OFF_XX), 256,512, nullptr,nullptr);

  for (int i=0;i<5;i++){
    build_hm<<<dim3(BT/16,4),128,0,stream>>>(Bf(OFF_H1), Bf(OFF_XX)+i*32, W_x2 + (size_t)i*32*CC, x_bias + i*CC, Bf(OFF_HM));
    if (i==0)      gemm128<EP_BF16><<<512,256,0,stream>>>(Bf(OFF_HM), Bf(WT_R), Bf(OFF_R), 256,512, nullptr,nullptr);
    else if (i==1){
      gemm_bf16<EP_TANH_BF16><<<dim3(BT/128,1),256,0,stream>>>(Bf(OFF_HM), Bf(WT_W1), Bf(OFF_W1T), 64,512, nullptr,nullptr,nullptr);
      gemm_bf16<EP_NEGEXP_F32><<<dim3(BT/128,4),256,0,stream>>>(Bf(OFF_W1T), Bf(WT_W2), F(OFF_WD), 256,64, nullptr,nullptr,b_w2);
    }
    else if (i==2) gemm128<EP_BF16><<<512,256,0,stream>>>(Bf(OFF_HM), Bf(WT_K), Bf(OFF_K), 256,512, nullptr,nullptr);
    else if (i==3) gemm128<EP_BF16><<<1024,256,0,stream>>>(Bf(OFF_HM), Bf(WT_V), Bf(OFF_V), 512,512, nullptr,nullptr);
    else           gemm128<EP_BF16><<<1024,256,0,stream>>>(Bf(OFF_HM), Bf(WT_G), Bf(OFF_G), 512,512, nullptr,nullptr);
  }

  // ---- WKV6 segment scan (SUB=32, NSUB=128); Mseg/Sstart in d_out ----
  wkv_p1<<<BB*4*NSUB,128,0,stream>>>(Bf(OFF_K), Bf(OFF_V), F(OFF_WD), Mseg, F(OFF_DSEG));
  wkv_p2<<<BB*4*8192/256,256,0,stream>>>(Mseg, F(OFF_DSEG));
  wkv_p3<<<BB*4*NSUB,128,0,stream>>>(Bf(OFF_R), Bf(OFF_K), Bf(OFF_V), F(OFF_WD), Mseg, u,
                                     Bf(OFF_G), gn_w, gn_b, Bf(OFF_H1));

  // ---- output projection + residual -> h2 (in d_out; overwrites Mseg) ----
  gemm128<EP_RES_F32><<<1024,256,0,stream>>>(Bf(OFF_H1), Bf(WT_O), h2, 512,512, x,nullptr);

  // ---- channel mixing (FFN) ----
  ln_bf16<<<BT,256,0,stream>>>(h2, ln2w, ln2b, Bf(OFF_HM));
  build_ffn_in<<<BT*CC/256,256,0,stream>>>(Bf(OFF_HM), mu_k, mu_r, Bf(OFF_R), Bf(OFF_V));
  gemm128<EP_RELU2_BF16><<<2048,256,0,stream>>>(Bf(OFF_R), Bf(WT_KEY), Bf(OFF_WD), 1024,512, nullptr,nullptr);
  gemm128<EP_SIG_BF16><<<1024,256,0,stream>>>(Bf(OFF_V), Bf(WT_REC), Bf(OFF_H1), 512,512, nullptr,nullptr);
  gemm128<EP_FINAL_F32><<<1024,256,0,stream>>>(Bf(OFF_WD), Bf(WT_VAL), h2, 512,1024, h2, Bf(OFF_H1));
}

// Round 8
// 1023.257 us; speedup vs baseline: 2.2062x; 1.0206x over previous
//
#include <hip/hip_runtime.h>
#include <hip/hip_bf16.h>
#include <math.h>

#define BB 8
#define TT 4096
#define CC 512
#define BT (BB*TT)
#define KD 256
#define VD 512
#define NSUB 128
#define SUB 32

using bf16 = __hip_bfloat16;
typedef __attribute__((ext_vector_type(2))) float f32x2;
typedef __attribute__((ext_vector_type(4))) float f32x4;
typedef __attribute__((ext_vector_type(8))) short s16x8;
typedef __attribute__((ext_vector_type(8))) unsigned short u16x8;
typedef const __attribute__((address_space(1))) unsigned int gu32;
typedef __attribute__((address_space(3))) unsigned int lu32;

static __device__ __forceinline__ float bf2f(bf16 x){ return __bfloat162float(x); }
static __device__ __forceinline__ bf16 f2bf(float x){ return __float2bfloat16(x); }
static __device__ __forceinline__ float bfbits(unsigned short u){
  union { unsigned int i; float f; } x; x.i = ((unsigned int)u)<<16; return x.f;
}
static __device__ __forceinline__ unsigned short f2bfbits(float f){
  union { bf16 b; unsigned short u; } x; x.b = f2bf(f); return x.u;
}
static __device__ __forceinline__ void gload16(const void* g, void* l){
  __builtin_amdgcn_global_load_lds((gu32*)g, (lu32*)l, 16, 0, 0);
}

// ---------------- workspace arena (bytes), peak ~217.3 MiB; Mseg lives in d_out ----------------
#define MiB 1048576ull
static constexpr size_t OFF_H1   = 0;           // bf16 BT*C (32)  ; p3 out GATED ; FFN RF
static constexpr size_t OFF_XX   = 32*MiB;      // bf16 BT*256 (16); dead by scan
static constexpr size_t OFF_DSEG = 32*MiB;      // f32 4096*64 (1) alias XX
static constexpr size_t OFF_HM   = 48*MiB;      // bf16 BT*C (32)  ; FFN HN
static constexpr size_t OFF_R    = 80*MiB;      // bf16 BT*256 (16); FFN KIN (spans R+K)
static constexpr size_t OFF_K    = 96*MiB;      // bf16 BT*256 (16)
static constexpr size_t OFF_V    = 112*MiB;     // bf16 BT*512 (32); FFN RIN
static constexpr size_t OFF_WD   = 144*MiB;     // f32 BT*256 (32) ; FFN KF low
static constexpr size_t OFF_G    = 176*MiB;     // bf16 BT*512 (32); FFN KF high
static constexpr size_t OFF_W1T  = 208*MiB;     // bf16 BT*64 (4)
static constexpr size_t WT_X1  = 212*MiB;            // 512x256 bf16
static constexpr size_t WT_R   = WT_X1  + 262144;
static constexpr size_t WT_K   = WT_R   + 262144;
static constexpr size_t WT_V   = WT_K   + 262144;
static constexpr size_t WT_G   = WT_V   + 524288;
static constexpr size_t WT_W1  = WT_G   + 524288;
static constexpr size_t WT_W2  = WT_W1  + 65536;
static constexpr size_t WT_O   = WT_W2  + 32768;
static constexpr size_t WT_KEY = WT_O   + 524288;
static constexpr size_t WT_REC = WT_KEY + 1048576;
static constexpr size_t WT_VAL = WT_REC + 524288;
static constexpr size_t WS_NEED = WT_VAL + 1048576;

// ---------------- fused weight convert+transpose for all 11 weights ----------------
__global__ void wconv_all(const float* s0, const float* s1, const float* s2, const float* s3,
                          const float* s4, const float* s5, const float* s6, const float* s7,
                          const float* s8, const float* s9, const float* s10, char* ws){
  struct E{int K,N,Npad; size_t off;};
  const E tab[11] = {
    {512,160,256,WT_X1},{512,256,256,WT_R},{512,256,256,WT_K},{512,512,512,WT_V},
    {512,512,512,WT_G},{512,64,64,WT_W1},{64,256,256,WT_W2},{512,512,512,WT_O},
    {512,1024,1024,WT_KEY},{512,512,512,WT_REC},{1024,512,512,WT_VAL}};
  const float* srcs[11] = {s0,s1,s2,s3,s4,s5,s6,s7,s8,s9,s10};
  int blk = blockIdx.x, i = 0, acc = 0;
  #pragma unroll 1
  for (; i<11; i++){ int nb = tab[i].K*tab[i].Npad/256; if (blk < acc+nb) break; acc += nb; }
  int idx = (blk-acc)*256 + threadIdx.x;
  int K = tab[i].K, N = tab[i].N;
  int n = idx / K, k = idx - n*K;
  float v = (n < N) ? srcs[i][(size_t)k*N + n] : 0.f;
  ((bf16*)(ws + tab[i].off))[idx] = f2bf(v);
}

// ---------------- LayerNorm over C=512, block per row, bf16 out ----------------
__global__ __launch_bounds__(256) void ln_bf16(const float* __restrict__ x, const float* __restrict__ w,
                                               const float* __restrict__ b, bf16* __restrict__ out){
  int bt = blockIdx.x;
  const float* row = x + (size_t)bt*CC;
  int t = threadIdx.x;
  float a0 = row[t], a1 = row[t+256];
  float s = a0 + a1, ss = a0*a0 + a1*a1;
  for (int off=32; off; off>>=1){ s += __shfl_down(s, off, 64); ss += __shfl_down(ss, off, 64); }
  __shared__ float ps[4], pss[4];
  int wv = t>>6, ln = t&63;
  if (ln==0){ ps[wv]=s; pss[wv]=ss; }
  __syncthreads();
  if (t==0){
    float S=ps[0]+ps[1]+ps[2]+ps[3], SS=pss[0]+pss[1]+pss[2]+pss[3];
    float mu = S/CC; float var = SS/CC - mu*mu;
    ps[0]=mu; pss[0]=rsqrtf(var+1e-5f);
  }
  __syncthreads();
  float mu = ps[0], inv = pss[0];
  out[(size_t)bt*CC + t]     = f2bf((a0-mu)*inv*w[t]+b[t]);
  out[(size_t)bt*CC + t+256] = f2bf((a1-mu)*inv*w[t+256]+b[t+256]);
}

// ---------------- xm = h + (shift(h)-h)*mu_x  (bf16 in/out) ----------------
__global__ void build_xm(const bf16* __restrict__ h, const float* __restrict__ mu_x, bf16* __restrict__ xm){
  size_t idx = (size_t)blockIdx.x*256 + threadIdx.x;
  int c = (int)(idx & (CC-1));
  size_t bt = idx >> 9;
  float hv = bf2f(h[idx]);
  float hp = (bt & (TT-1)) ? bf2f(h[idx - CC]) : 0.f;
  xm[idx] = f2bf(hv + (hp - hv)*mu_x[c]);
}

// ---------------- single lerp-mix build: hm = h + (hprev-h)*(xx_i @ W_x2[i] + bias_i) -------
__global__ __launch_bounds__(128) void build_hm(const bf16* __restrict__ h, const bf16* __restrict__ xx,
        const float* __restrict__ W_x2i, const float* __restrict__ x_biasi, bf16* __restrict__ hm){
  int bt0 = blockIdx.x*16;
  int c = blockIdx.y*128 + threadIdx.x;
  float W[32];
  #pragma unroll
  for (int r=0;r<32;r++) W[r] = W_x2i[(size_t)r*CC + c];
  float bia = x_biasi[c];
  #pragma unroll 1
  for (int j=0;j<16;j++){
    int bt = bt0+j;
    float hv = bf2f(h[(size_t)bt*CC + c]);
    float hp = ((bt & (TT-1)) != 0) ? bf2f(h[(size_t)(bt-1)*CC + c]) : 0.f;
    const bf16* xr = xx + (size_t)bt*256;
    float acc = bia;
    #pragma unroll
    for (int r=0;r<32;r++) acc += bf2f(xr[r])*W[r];
    hm[(size_t)bt*CC + c] = f2bf(hv + (hp-hv)*acc);
  }
}

// ---------------- epilogue modes ----------------
enum {EP_BF16, EP_TANH_BF16, EP_NEGEXP_F32, EP_RES_F32, EP_RELU2_BF16, EP_SIG_BF16, EP_FINAL_F32};

// ---------------- m97-style 128x128 MFMA GEMM with global_load_lds staging -------------
template<int MODE>
__global__ __launch_bounds__(256) void gemm128(
    const bf16* __restrict__ A, const bf16* __restrict__ Bt, void* __restrict__ Out,
    int N, int K, const float* __restrict__ auxf, const bf16* __restrict__ auxb)
{
  __shared__ bf16 Al[128][32];
  __shared__ bf16 Bl[128][32];
  int tid = threadIdx.x;
  int nbk = N>>7;
  int q8 = gridDim.x>>3;
  int o = (blockIdx.x & 7)*q8 + (blockIdx.x>>3);
  int nb = o % nbk, mb = o / nbk;
  int m0 = mb*128, n0 = nb*128;
  int wv = tid>>6, ln = tid&63;
  int wr = wv>>1, wc = wv&1;
  f32x4 acc[4][4];
  #pragma unroll
  for (int i=0;i<4;i++) for (int j=0;j<4;j++){ f32x4 z={0.f,0.f,0.f,0.f}; acc[i][j]=z; }
  int r0 = tid>>2, k0 = (tid&3)*8;
  const int nkt = K>>5;
  for (int kt=0; kt<nkt; kt++){
    const bf16* ga = A  + (size_t)(m0+r0)*K + kt*32 + k0;
    const bf16* gb = Bt + (size_t)(n0+r0)*K + kt*32 + k0;
    gload16(ga,                 (char*)&Al[0][0] + tid*16);
    gload16(ga + (size_t)64*K,  (char*)&Al[0][0] + (tid+256)*16);
    gload16(gb,                 (char*)&Bl[0][0] + tid*16);
    gload16(gb + (size_t)64*K,  (char*)&Bl[0][0] + (tid+256)*16);
    __syncthreads();
    int ks = (ln>>4)*8;
    s16x8 af[4], bq[4];
    #pragma unroll
    for (int i=0;i<4;i++){
      af[i] = *(const s16x8*)&Al[wr*64 + i*16 + (ln&15)][ks];
      bq[i] = *(const s16x8*)&Bl[wc*64 + i*16 + (ln&15)][ks];
    }
    #pragma unroll
    for (int mi=0;mi<4;mi++)
      #pragma unroll
      for (int ni=0;ni<4;ni++)
        acc[mi][ni] = __builtin_amdgcn_mfma_f32_16x16x32_bf16(af[mi], bq[ni], acc[mi][ni], 0,0,0);
    __syncthreads();
  }
  #pragma unroll
  for (int mi=0;mi<4;mi++)
    #pragma unroll
    for (int ni=0;ni<4;ni++){
      int col = n0 + wc*64 + ni*16 + (ln&15);
      int rb  = m0 + wr*64 + mi*16 + (ln>>4)*4;
      #pragma unroll
      for (int j=0;j<4;j++){
        size_t idx = (size_t)(rb+j)*N + col;
        float val = acc[mi][ni][j];
        if constexpr(MODE==EP_BF16)           ((bf16*)Out)[idx] = f2bf(val);
        else if constexpr(MODE==EP_TANH_BF16) ((bf16*)Out)[idx] = f2bf(tanhf(val));
        else if constexpr(MODE==EP_RES_F32)   ((float*)Out)[idx] = auxf[idx] + val;
        else if constexpr(MODE==EP_RELU2_BF16){ float m = fmaxf(val,0.f); ((bf16*)Out)[idx] = f2bf(m*m); }
        else if constexpr(MODE==EP_SIG_BF16)  ((bf16*)Out)[idx] = f2bf(1.f/(1.f+expf(-val)));
        else if constexpr(MODE==EP_FINAL_F32) ((float*)Out)[idx] = auxf[idx] + bf2f(auxb[idx])*val;
      }
    }
}

// ---------------- small-N GEMM (used for W1 N=64 and W2 K=64) -------------
template<int MODE>
__global__ __launch_bounds__(256) void gemm_bf16(
    const bf16* __restrict__ A, const bf16* __restrict__ Bt, void* __restrict__ Out,
    int N, int K, const float* __restrict__ auxf, const bf16* __restrict__ auxb,
    const float* __restrict__ bias)
{
  __shared__ bf16 Al[128][40];
  __shared__ bf16 Bl[64][40];
  int tid = threadIdx.x;
  int m0 = blockIdx.x*128, n0 = blockIdx.y*64;
  int wv = tid>>6, ln = tid&63;
  f32x4 acc[2][4];
  #pragma unroll
  for(int f=0;f<2;f++) for(int c=0;c<4;c++){ f32x4 z = {0.f,0.f,0.f,0.f}; acc[f][c]=z; }
  const int nkt = K>>5;
  for (int kt=0; kt<nkt; kt++){
    __syncthreads();
    {
      int c0 = tid, c1 = tid+256;
      int r = c0>>2, ko=(c0&3)*8;
      *(uint4*)&Al[r][ko] = *(const uint4*)&A[(size_t)(m0+r)*K + kt*32 + ko];
      r = c1>>2; ko=(c1&3)*8;
      *(uint4*)&Al[r][ko] = *(const uint4*)&A[(size_t)(m0+r)*K + kt*32 + ko];
      r = tid>>2; ko=(tid&3)*8;
      *(uint4*)&Bl[r][ko] = *(const uint4*)&Bt[(size_t)(n0+r)*K + kt*32 + ko];
    }
    __syncthreads();
    int ks = (ln>>4)*8;
    s16x8 af0 = *(const s16x8*)&Al[wv*32 + (ln&15)][ks];
    s16x8 af1 = *(const s16x8*)&Al[wv*32 + 16 + (ln&15)][ks];
    #pragma unroll
    for (int c=0;c<4;c++){
      s16x8 bfr = *(const s16x8*)&Bl[c*16 + (ln&15)][ks];
      acc[0][c] = __builtin_amdgcn_mfma_f32_16x16x32_bf16(af0, bfr, acc[0][c], 0,0,0);
      acc[1][c] = __builtin_amdgcn_mfma_f32_16x16x32_bf16(af1, bfr, acc[1][c], 0,0,0);
    }
  }
  #pragma unroll
  for (int f=0; f<2; f++) for (int c=0;c<4;c++){
    int col = n0 + c*16 + (ln&15);
    int rbase = m0 + wv*32 + f*16 + (ln>>4)*4;
    #pragma unroll
    for (int j=0;j<4;j++){
      size_t idx = (size_t)(rbase+j)*N + col;
      float val = acc[f][c][j];
      if constexpr(MODE==EP_TANH_BF16)      ((bf16*)Out)[idx] = f2bf(tanhf(val));
      else if constexpr(MODE==EP_NEGEXP_F32){ float w = -expf(val + bias[col]); ((float*)Out)[idx] = fmaxf(w, -20.f); }
    }
  }
}

// ---------------- WKV6 segment scan (32-token chunks, NSUB=128) ----------------
// P1: 2 waves/block; wave owns 64 v-cols; lane = k. State as f32x2[32] (v_pk_fma_f32).
__global__ __launch_bounds__(128,3) void wkv_p1(const bf16* __restrict__ kbuf, const bf16* __restrict__ vbuf,
      const float* __restrict__ wd, bf16* __restrict__ Mseg, float* __restrict__ Dseg){
  int bhs = blockIdx.x; int bh = bhs>>7, sub = bhs&127;
  int b = bh>>2, h = bh&3;
  int tid = threadIdx.x, wv = tid>>6, ln = tid&63;
  __shared__ float vtile[16][132];
  int t0 = sub*SUB;
  size_t kqbase = ((size_t)b*TT + t0)*KD + h*64 + ln;
  float csum = 0.f;
  f32x2 S2[32];
  #pragma unroll
  for (int p=0;p<32;p++){ f32x2 z={0.f,0.f}; S2[p]=z; }
  float wnxt = wd[kqbase];
  unsigned short qnxt = ((const unsigned short*)kbuf)[kqbase];
  #pragma unroll 1
  for (int tile=0; tile<2; tile++){
    int tb = t0 + tile*16;
    __syncthreads();
    {
      int t = tid>>3, c = (tid&7)*16;
      const unsigned short* vg = (const unsigned short*)vbuf + ((size_t)b*TT + tb + t)*VD + h*128 + c;
      u16x8 a8 = *(const u16x8*)vg;
      u16x8 b8 = *(const u16x8*)(vg+8);
      #pragma unroll
      for (int e=0;e<8;e++){ vtile[t][c+e] = bfbits(a8[e]); vtile[t][c+8+e] = bfbits(b8[e]); }
    }
    __syncthreads();
    #pragma unroll 1
    for (int tt=0;tt<16;tt++){
      int lt = tile*16+tt;
      float wcur = wnxt; unsigned short qcur = qnxt;
      if (lt < SUB-1){
        size_t gi = kqbase + (size_t)(lt+1)*KD;
        wnxt = wd[gi]; qnxt = ((const unsigned short*)kbuf)[gi];
      }
      csum += wcur;
      float e = expf(wcur), qv = bfbits(qcur);
      f32x2 e2 = {e,e}, q2 = {qv,qv};
      #pragma unroll
      for (int vg=0;vg<16;vg++){
        f32x4 vvv = *(const f32x4*)&vtile[tt][wv*64 + vg*4];
        f32x2 vA = {vvv[0], vvv[1]}, vB = {vvv[2], vvv[3]};
        S2[vg*2]   = e2*S2[vg*2]   + q2*vA;
        S2[vg*2+1] = e2*S2[vg*2+1] + q2*vB;
      }
    }
  }
  unsigned short* M = (unsigned short*)Mseg + (size_t)bhs*8192 + (size_t)ln*128 + wv*64;
  #pragma unroll
  for (int vg=0; vg<16; vg++){
    ushort4 s4;
    s4.x = f2bfbits(S2[vg*2][0]);   s4.y = f2bfbits(S2[vg*2][1]);
    s4.z = f2bfbits(S2[vg*2+1][0]); s4.w = f2bfbits(S2[vg*2+1][1]);
    *(ushort4*)&M[vg*4] = s4;
  }
  if (wv==0) Dseg[(size_t)bhs*64 + ln] = expf(csum);
}

// P2: sequential combine across sub-chunks, IN-PLACE bf16 (Mseg becomes Sstart)
__global__ __launch_bounds__(256) void wkv_p2(bf16* __restrict__ MS, const float* __restrict__ Dseg){
  int idx = blockIdx.x*256 + threadIdx.x;
  int bh = idx>>13; int k = (idx>>7)&63; int v = idx&127;
  bf16* p = MS + (size_t)bh*NSUB*8192 + k*128 + v;
  const float* d = Dseg + (size_t)bh*NSUB*64 + k;
  float S = 0.f;
  float m = bf2f(p[0]); float D = d[0];
  #pragma unroll 1
  for (int seg=0; seg<NSUB; seg++){
    float mN=0.f, DN=0.f;
    if (seg < NSUB-1){ mN = bf2f(p[(size_t)(seg+1)*8192]); DN = d[(seg+1)*64]; }
    p[(size_t)seg*8192] = f2bf(S);
    S = D*S + m;
    m = mN; D = DN;
  }
}

// P3: v-lane layout, f32x2-packed fully-unrolled k loop (v_pk_fma_f32).
// 128 threads = 128 v-channels; per-thread state S2[32] = 64 f32; GN via 16-lane-group reduce.
__global__ __launch_bounds__(128,3) void wkv_p3(const bf16* __restrict__ rbuf, const bf16* __restrict__ kbuf,
     const bf16* __restrict__ vbuf, const float* __restrict__ wd, const bf16* __restrict__ Sstart,
     const float* __restrict__ uu, const bf16* __restrict__ gg,
     const float* __restrict__ gn_w, const float* __restrict__ gn_b, bf16* __restrict__ gated){
  int bhs = blockIdx.x; int bh = bhs>>7, sub = bhs&127;
  int b = bh>>2, h = bh&3;
  int tid = threadIdx.x;
  __shared__ float ew[8][68], qk[8][68], rr[8][68], bu[8];
  __shared__ unsigned short vtb[8][128];
  __shared__ float ot[8][132];
  int tq = tid>>4, cq4 = (tid&15)*4, cq8 = (tid&15)*8;
  float4 u4 = *(const float4*)&uu[h*64 + cq4];
  f32x2 S2[32];
  const unsigned short* Sst = (const unsigned short*)Sstart + (size_t)bhs*8192;
  #pragma unroll
  for (int p=0;p<32;p++){
    f32x2 s = { bfbits(Sst[(2*p)*128 + tid]), bfbits(Sst[(2*p+1)*128 + tid]) };
    S2[p] = s;
  }
  int t0 = sub*SUB;
  #pragma unroll 1
  for (int tile=0; tile<4; tile++){
    int tb = t0 + tile*8;
    // ---- stage 8 tokens of e/q/r/bu/v ----
    {
      float4 w4 = *(const float4*)&wd[((size_t)b*TT + tb + tq)*KD + h*64 + cq4];
      ew[tq][cq4+0]=expf(w4.x); ew[tq][cq4+1]=expf(w4.y); ew[tq][cq4+2]=expf(w4.z); ew[tq][cq4+3]=expf(w4.w);
      size_t gi = ((size_t)b*TT + tb + tq)*KD + h*64 + cq4;
      ushort4 k4 = *(const ushort4*)&((const unsigned short*)kbuf)[gi];
      ushort4 r4 = *(const ushort4*)&((const unsigned short*)rbuf)[gi];
      float q0=bfbits(k4.x),q1=bfbits(k4.y),q2=bfbits(k4.z),q3=bfbits(k4.w);
      float rv0=bfbits(r4.x),rv1=bfbits(r4.y),rv2=bfbits(r4.z),rv3=bfbits(r4.w);
      qk[tq][cq4+0]=q0; qk[tq][cq4+1]=q1; qk[tq][cq4+2]=q2; qk[tq][cq4+3]=q3;
      rr[tq][cq4+0]=rv0; rr[tq][cq4+1]=rv1; rr[tq][cq4+2]=rv2; rr[tq][cq4+3]=rv3;
      float part = rv0*q0*u4.x + rv1*q1*u4.y + rv2*q2*u4.z + rv3*q3*u4.w;
      part += __shfl_xor(part,1,64); part += __shfl_xor(part,2,64);
      part += __shfl_xor(part,4,64); part += __shfl_xor(part,8,64);
      if ((tid&15)==0) bu[tq] = part;
      *(u16x8*)&vtb[tq][cq8] = *(const u16x8*)&((const unsigned short*)vbuf)[((size_t)b*TT + tb + tq)*VD + h*128 + cq8];
    }
    __syncthreads();
    // ---- scan 8 tokens; o lane-local; packed k loop fully unrolled ----
    #pragma unroll 1
    for (int t=0;t<8;t++){
      float vl = bfbits(vtb[t][tid]);
      f32x2 vl2 = {vl, vl};
      f32x2 o2 = {0.f, 0.f};
      #pragma unroll
      for (int g=0;g<16;g++){
        f32x4 e4 = *(const f32x4*)&ew[t][g*4];
        f32x4 q4 = *(const f32x4*)&qk[t][g*4];
        f32x4 r4 = *(const f32x4*)&rr[t][g*4];
        f32x2 eA = {e4[0],e4[1]}, eB = {e4[2],e4[3]};
        f32x2 qA = {q4[0],q4[1]}, qB = {q4[2],q4[3]};
        f32x2 rA = {r4[0],r4[1]}, rB = {r4[2],r4[3]};
        int p = g*2;
        o2 += rA*S2[p];   S2[p]   = eA*S2[p]   + qA*vl2;
        o2 += rB*S2[p+1]; S2[p+1] = eB*S2[p+1] + qB*vl2;
      }
      float o = o2[0] + o2[1] + bu[t]*vl;
      ot[t][tid] = o;
    }
    __syncthreads();
    // ---- GN + silu gate: thread handles token tq, channels cq8..cq8+7 ----
    {
      float gw[8], gb[8];
      *(float4*)&gw[0] = *(const float4*)&gn_w[h*128+cq8];
      *(float4*)&gw[4] = *(const float4*)&gn_w[h*128+cq8+4];
      *(float4*)&gb[0] = *(const float4*)&gn_b[h*128+cq8];
      *(float4*)&gb[4] = *(const float4*)&gn_b[h*128+cq8+4];
      float o8[8];
      *(float4*)&o8[0] = *(const float4*)&ot[tq][cq8];
      *(float4*)&o8[4] = *(const float4*)&ot[tq][cq8+4];
      float s = 0.f, ss = 0.f;
      #pragma unroll
      for (int e=0;e<8;e++){ s += o8[e]; ss += o8[e]*o8[e]; }
      s += __shfl_xor(s,1,64); ss += __shfl_xor(ss,1,64);
      s += __shfl_xor(s,2,64); ss += __shfl_xor(ss,2,64);
      s += __shfl_xor(s,4,64); ss += __shfl_xor(ss,4,64);
      s += __shfl_xor(s,8,64); ss += __shfl_xor(ss,8,64);
      float mu = s*(1.f/128.f);
      float inv = rsqrtf(fmaxf(ss*(1.f/128.f) - mu*mu, 0.f) + 1e-5f);
      size_t go = ((size_t)b*TT + tb + tq)*VD + h*128 + cq8;
      u16x8 g8 = *(const u16x8*)&((const unsigned short*)gg)[go];
      u16x8 out8;
      #pragma unroll
      for (int e=0;e<8;e++){
        float xv = (o8[e]-mu)*inv*gw[e] + gb[e];
        float ga = bfbits(g8[e]);
        xv *= ga/(1.f+expf(-ga));
        out8[e] = f2bfbits(xv);
      }
      *(u16x8*)&((unsigned short*)gated)[go] = out8;
    }
    __syncthreads();
  }
}

// ---------------- FFN lerp inputs (bf16 in/out) ----------------
__global__ void build_ffn_in(const bf16* __restrict__ hn, const float* __restrict__ mu_k,
                             const float* __restrict__ mu_r, bf16* __restrict__ kin, bf16* __restrict__ rin){
  size_t idx = (size_t)blockIdx.x*256 + threadIdx.x;
  int c = (int)(idx & (CC-1));
  size_t bt = idx >> 9;
  float hv = bf2f(hn[idx]);
  float hp = (bt & (TT-1)) ? bf2f(hn[idx - CC]) : 0.f;
  float d = hp - hv;
  kin[idx] = f2bf(hv + d*mu_k[c]);
  rin[idx] = f2bf(hv + d*mu_r[c]);
}

extern "C" void kernel_launch(void* const* d_in, const int* in_sizes, int n_in,
                              void* d_out, int out_size, void* d_ws, size_t ws_size,
                              hipStream_t stream){
  (void)in_sizes; (void)n_in; (void)out_size;
  if (ws_size < WS_NEED) return;
  const float* x      = (const float*)d_in[0];
  const float* ln1w   = (const float*)d_in[1];
  const float* ln1b   = (const float*)d_in[2];
  const float* mu_x   = (const float*)d_in[3];
  const float* W_x1   = (const float*)d_in[4];
  const float* W_x2   = (const float*)d_in[5];
  const float* x_bias = (const float*)d_in[6];
  const float* W_r    = (const float*)d_in[7];
  const float* W_k    = (const float*)d_in[8];
  const float* W_v    = (const float*)d_in[9];
  const float* W_g    = (const float*)d_in[10];
  const float* W_w1   = (const float*)d_in[11];
  const float* W_w2   = (const float*)d_in[12];
  const float* b_w2   = (const float*)d_in[13];
  const float* u      = (const float*)d_in[14];
  const float* gn_w   = (const float*)d_in[15];
  const float* gn_b   = (const float*)d_in[16];
  const float* W_o    = (const float*)d_in[17];
  const float* ln2w   = (const float*)d_in[18];
  const float* ln2b   = (const float*)d_in[19];
  const float* mu_k   = (const float*)d_in[20];
  const float* W_key  = (const float*)d_in[21];
  const float* mu_r   = (const float*)d_in[22];
  const float* W_rec  = (const float*)d_in[23];
  const float* W_val  = (const float*)d_in[24];
  char* ws = (char*)d_ws;
  auto F  = [&](size_t off){ return (float*)(ws+off); };
  auto Bf = [&](size_t off){ return (bf16*)(ws+off); };
  float* h2 = (float*)d_out;        // attn-out residual lives in d_out
  bf16* Mseg = (bf16*)d_out;        // scan summaries alias d_out (dead before O-gemm)

  // fused weight conversions (9920 blocks)
  wconv_all<<<9920,256,0,stream>>>(W_x1,W_r,W_k,W_v,W_g,W_w1,W_w2,W_o,W_key,W_rec,W_val, ws);

  // ---- attention pre-projections ----
  ln_bf16<<<BT,256,0,stream>>>(x, ln1w, ln1b, Bf(OFF_H1));
  build_xm<<<BT*CC/256,256,0,stream>>>(Bf(OFF_H1), mu_x, Bf(OFF_HM));
  gemm128<EP_TANH_BF16><<<512,256,0,stream>>>(Bf(OFF_HM), Bf(WT_X1), Bf(OFF_XX), 256,512, nullptr,nullptr);

  for (int i=0;i<5;i++){
    build_hm<<<dim3(BT/16,4),128,0,stream>>>(Bf(OFF_H1), Bf(OFF_XX)+i*32, W_x2 + (size_t)i*32*CC, x_bias + i*CC, Bf(OFF_HM));
    if (i==0)      gemm128<EP_BF16><<<512,256,0,stream>>>(Bf(OFF_HM), Bf(WT_R), Bf(OFF_R), 256,512, nullptr,nullptr);
    else if (i==1){
      gemm_bf16<EP_TANH_BF16><<<dim3(BT/128,1),256,0,stream>>>(Bf(OFF_HM), Bf(WT_W1), Bf(OFF_W1T), 64,512, nullptr,nullptr,nullptr);
      gemm_bf16<EP_NEGEXP_F32><<<dim3(BT/128,4),256,0,stream>>>(Bf(OFF_W1T), Bf(WT_W2), F(OFF_WD), 256,64, nullptr,nullptr,b_w2);
    }
    else if (i==2) gemm128<EP_BF16><<<512,256,0,stream>>>(Bf(OFF_HM), Bf(WT_K), Bf(OFF_K), 256,512, nullptr,nullptr);
    else if (i==3) gemm128<EP_BF16><<<1024,256,0,stream>>>(Bf(OFF_HM), Bf(WT_V), Bf(OFF_V), 512,512, nullptr,nullptr);
    else           gemm128<EP_BF16><<<1024,256,0,stream>>>(Bf(OFF_HM), Bf(WT_G), Bf(OFF_G), 512,512, nullptr,nullptr);
  }

  // ---- WKV6 segment scan (SUB=32, NSUB=128); Mseg/Sstart in d_out ----
  wkv_p1<<<BB*4*NSUB,128,0,stream>>>(Bf(OFF_K), Bf(OFF_V), F(OFF_WD), Mseg, F(OFF_DSEG));
  wkv_p2<<<BB*4*8192/256,256,0,stream>>>(Mseg, F(OFF_DSEG));
  wkv_p3<<<BB*4*NSUB,128,0,stream>>>(Bf(OFF_R), Bf(OFF_K), Bf(OFF_V), F(OFF_WD), Mseg, u,
                                     Bf(OFF_G), gn_w, gn_b, Bf(OFF_H1));

  // ---- output projection + residual -> h2 (in d_out; overwrites Mseg) ----
  gemm128<EP_RES_F32><<<1024,256,0,stream>>>(Bf(OFF_H1), Bf(WT_O), h2, 512,512, x,nullptr);

  // ---- channel mixing (FFN) ----
  ln_bf16<<<BT,256,0,stream>>>(h2, ln2w, ln2b, Bf(OFF_HM));
  build_ffn_in<<<BT*CC/256,256,0,stream>>>(Bf(OFF_HM), mu_k, mu_r, Bf(OFF_R), Bf(OFF_V));
  gemm128<EP_RELU2_BF16><<<2048,256,0,stream>>>(Bf(OFF_R), Bf(WT_KEY), Bf(OFF_WD), 1024,512, nullptr,nullptr);
  gemm128<EP_SIG_BF16><<<1024,256,0,stream>>>(Bf(OFF_V), Bf(WT_REC), Bf(OFF_H1), 512,512, nullptr,nullptr);
  gemm128<EP_FINAL_F32><<<1024,256,0,stream>>>(Bf(OFF_WD), Bf(WT_VAL), h2, 512,1024, h2, Bf(OFF_H1));
}

// Round 9
// 941.103 us; speedup vs baseline: 2.3988x; 1.0873x over previous
//
#include <hip/hip_runtime.h>
#include <hip/hip_bf16.h>
#include <hip/hip_fp16.h>
#include <math.h>

#define BB 8
#define TT 4096
#define CC 512
#define BT (BB*TT)
#define KD 256
#define VD 512
#define NSUB 64
#define SUB 64

using bf16 = __hip_bfloat16;
using f16 = _Float16;
typedef __attribute__((ext_vector_type(2))) float f32x2;
typedef __attribute__((ext_vector_type(4))) float f32x4;
typedef __attribute__((ext_vector_type(8))) short s16x8;
typedef __attribute__((ext_vector_type(8))) unsigned short u16x8;
typedef const __attribute__((address_space(1))) unsigned int gu32;
typedef __attribute__((address_space(3))) unsigned int lu32;

static __device__ __forceinline__ float bf2f(bf16 x){ return __bfloat162float(x); }
static __device__ __forceinline__ bf16 f2bf(float x){ return __float2bfloat16(x); }
static __device__ __forceinline__ float bfbits(unsigned short u){
  union { unsigned int i; float f; } x; x.i = ((unsigned int)u)<<16; return x.f;
}
static __device__ __forceinline__ unsigned short f2bfbits(float f){
  union { bf16 b; unsigned short u; } x; x.b = f2bf(f); return x.u;
}
static __device__ __forceinline__ float h2f(unsigned short u){
  f16 h; __builtin_memcpy(&h,&u,2); return (float)h;
}
static __device__ __forceinline__ void gload16(const void* g, void* l){
  __builtin_amdgcn_global_load_lds((gu32*)g, (lu32*)l, 16, 0, 0);
}

// ---------------- workspace arena (bytes); Mseg lives in d_out ----------------
#define MiB 1048576ull
static constexpr size_t OFF_H1   = 0;           // bf16 BT*C (32)  ; p3 out GATED ; FFN RF
static constexpr size_t OFF_XX   = 32*MiB;      // bf16 BT*256 (16); dead by scan
static constexpr size_t OFF_DSEG = 32*MiB;      // f32 2048*64 (0.5) alias XX
static constexpr size_t OFF_HM   = 48*MiB;      // bf16 BT*C (32) = hm0 ; FFN HN
static constexpr size_t OFF_R    = 80*MiB;      // bf16 BT*256 (16); FFN KIN (spans R+K)
static constexpr size_t OFF_K    = 96*MiB;      // bf16 BT*256 (16)
static constexpr size_t OFF_V    = 112*MiB;     // bf16 BT*512 (32); FFN RIN
static constexpr size_t OFF_WD   = 144*MiB;     // f16 BT*256 (16) ew; build: hm4 (32); FFN KF low
static constexpr size_t OFF_G    = 176*MiB;     // bf16 BT*512 (32) g; build: hm3 ; FFN KF high
static constexpr size_t OFF_W1T  = 208*MiB;     // bf16 BT*64 (4)
static constexpr size_t WT_X1  = 212*MiB;            // 512x256 bf16
static constexpr size_t WT_R   = WT_X1  + 262144;
static constexpr size_t WT_K   = WT_R   + 262144;
static constexpr size_t WT_V   = WT_K   + 262144;
static constexpr size_t WT_G   = WT_V   + 524288;
static constexpr size_t WT_W1  = WT_G   + 524288;
static constexpr size_t WT_W2  = WT_W1  + 65536;
static constexpr size_t WT_O   = WT_W2  + 32768;
static constexpr size_t WT_KEY = WT_O   + 524288;
static constexpr size_t WT_REC = WT_KEY + 1048576;
static constexpr size_t WT_VAL = WT_REC + 524288;
static constexpr size_t WS_NEED = WT_VAL + 1048576;

// ---------------- tiled transposed weight convert (coalesced both sides) ----------------
__global__ __launch_bounds__(256) void wconv_t2(const float* s0, const float* s1, const float* s2,
        const float* s3, const float* s4, const float* s5, const float* s6, const float* s7,
        const float* s8, const float* s9, const float* s10, char* ws){
  struct E{int K,N,Npad; size_t off;};
  const E tab[11] = {
    {512,160,256,WT_X1},{512,256,256,WT_R},{512,256,256,WT_K},{512,512,512,WT_V},
    {512,512,512,WT_G},{512,64,64,WT_W1},{64,256,256,WT_W2},{512,512,512,WT_O},
    {512,1024,1024,WT_KEY},{512,512,512,WT_REC},{1024,512,512,WT_VAL}};
  const float* srcs[11] = {s0,s1,s2,s3,s4,s5,s6,s7,s8,s9,s10};
  int blk = blockIdx.x, i = 0, acc = 0;
  #pragma unroll 1
  for (; i<11; i++){ int nt = (tab[i].K>>6)*(tab[i].Npad>>6); if (blk < acc+nt) break; acc += nt; }
  int local = blk - acc;
  int K = tab[i].K, N = tab[i].N;
  int ntn = tab[i].Npad>>6;
  int k0 = (local/ntn)*64, n0 = (local%ntn)*64;
  const float* src = srcs[i];
  bf16* dst = (bf16*)(ws + tab[i].off);
  __shared__ float T[64][65];
  int t = threadIdx.x;
  #pragma unroll
  for (int e=0;e<16;e++){
    int idx = t + e*256; int r = idx>>6, c = idx&63;
    int n = n0 + c;
    T[r][c] = (n < N) ? src[(size_t)(k0+r)*N + n] : 0.f;
  }
  __syncthreads();
  #pragma unroll
  for (int e=0;e<16;e++){
    int idx = t + e*256; int r = idx>>6, c = idx&63;
    dst[(size_t)(n0+r)*K + k0 + c] = f2bf(T[c][r]);
  }
}

// ---------------- LayerNorm over C=512, block per row, bf16 out ----------------
__global__ __launch_bounds__(256) void ln_bf16(const float* __restrict__ x, const float* __restrict__ w,
                                               const float* __restrict__ b, bf16* __restrict__ out){
  int bt = blockIdx.x;
  const float* row = x + (size_t)bt*CC;
  int t = threadIdx.x;
  float a0 = row[t], a1 = row[t+256];
  float s = a0 + a1, ss = a0*a0 + a1*a1;
  for (int off=32; off; off>>=1){ s += __shfl_down(s, off, 64); ss += __shfl_down(ss, off, 64); }
  __shared__ float ps[4], pss[4];
  int wv = t>>6, ln = t&63;
  if (ln==0){ ps[wv]=s; pss[wv]=ss; }
  __syncthreads();
  if (t==0){
    float S=ps[0]+ps[1]+ps[2]+ps[3], SS=pss[0]+pss[1]+pss[2]+pss[3];
    float mu = S/CC; float var = SS/CC - mu*mu;
    ps[0]=mu; pss[0]=rsqrtf(var+1e-5f);
  }
  __syncthreads();
  float mu = ps[0], inv = pss[0];
  out[(size_t)bt*CC + t]     = f2bf((a0-mu)*inv*w[t]+b[t]);
  out[(size_t)bt*CC + t+256] = f2bf((a1-mu)*inv*w[t+256]+b[t+256]);
}

// ---------------- xm = h + (shift(h)-h)*mu_x  (bf16, 8 elems/thread) ----------------
__global__ void build_xm(const bf16* __restrict__ h, const float* __restrict__ mu_x, bf16* __restrict__ xm){
  size_t base = ((size_t)blockIdx.x*256 + threadIdx.x)*8;
  int c = (int)(base & (CC-1));
  size_t bt = base >> 9;
  u16x8 hv8 = *(const u16x8*)&((const unsigned short*)h)[base];
  u16x8 hp8;
  if (bt & (TT-1)) hp8 = *(const u16x8*)&((const unsigned short*)h)[base - CC];
  else { hp8 = u16x8{0,0,0,0,0,0,0,0}; }
  float m8[8];
  *(float4*)&m8[0] = *(const float4*)&mu_x[c];
  *(float4*)&m8[4] = *(const float4*)&mu_x[c+4];
  u16x8 o8;
  #pragma unroll
  for (int e=0;e<8;e++){
    float f = bfbits(hv8[e]), p = bfbits(hp8[e]);
    o8[e] = f2bfbits(f + (p-f)*m8[e]);
  }
  *(u16x8*)&((unsigned short*)xm)[base] = o8;
}

// ---------------- fused 5-way lerp-mix build: hm_i = h + (hprev-h)*(xx_i @ W_x2[i] + bias_i) ----
__global__ __launch_bounds__(128) void build_hm5(const bf16* __restrict__ h, const bf16* __restrict__ xx,
        const float* __restrict__ W_x2, const float* __restrict__ x_bias,
        bf16* hm0, bf16* hm1, bf16* hm2, bf16* hm3, bf16* hm4){
  int bt0 = blockIdx.x*16;
  int c = blockIdx.y*128 + threadIdx.x;
  float hv[16], hp[16];
  #pragma unroll
  for (int j=0;j<16;j++){
    int bt = bt0+j;
    hv[j] = bf2f(h[(size_t)bt*CC + c]);
    hp[j] = ((bt & (TT-1)) != 0) ? bf2f(h[(size_t)(bt-1)*CC + c]) : 0.f;
  }
  bf16* outs[5] = {hm0,hm1,hm2,hm3,hm4};
  #pragma unroll 1
  for (int i=0;i<5;i++){
    float W[32];
    #pragma unroll
    for (int r=0;r<32;r++) W[r] = W_x2[(size_t)(i*32+r)*CC + c];
    float bia = x_bias[i*CC + c];
    bf16* o = outs[i];
    #pragma unroll 1
    for (int j=0;j<16;j++){
      const bf16* xr = xx + (size_t)(bt0+j)*256 + i*32;
      float acc = bia;
      #pragma unroll
      for (int r=0;r<32;r++) acc += bf2f(xr[r])*W[r];
      o[(size_t)(bt0+j)*CC + c] = f2bf(hv[j] + (hp[j]-hv[j])*acc);
    }
  }
}

// ---------------- epilogue modes ----------------
enum {EP_BF16, EP_TANH_BF16, EP_NEGEXP_F16, EP_RES_F32, EP_RELU2_BF16, EP_SIG_BF16, EP_FINAL_F32};

// ---------------- m97-style 128x128 MFMA GEMM with global_load_lds staging -------------
template<int MODE>
__global__ __launch_bounds__(256) void gemm128(
    const bf16* __restrict__ A, const bf16* __restrict__ Bt, void* __restrict__ Out,
    int N, int K, const float* __restrict__ auxf, const bf16* __restrict__ auxb)
{
  __shared__ bf16 Al[128][32];
  __shared__ bf16 Bl[128][32];
  int tid = threadIdx.x;
  int nbk = N>>7;
  int q8 = gridDim.x>>3;
  int o = (blockIdx.x & 7)*q8 + (blockIdx.x>>3);
  int nb = o % nbk, mb = o / nbk;
  int m0 = mb*128, n0 = nb*128;
  int wv = tid>>6, ln = tid&63;
  int wr = wv>>1, wc = wv&1;
  f32x4 acc[4][4];
  #pragma unroll
  for (int i=0;i<4;i++) for (int j=0;j<4;j++){ f32x4 z={0.f,0.f,0.f,0.f}; acc[i][j]=z; }
  int r0 = tid>>2, k0 = (tid&3)*8;
  const int nkt = K>>5;
  for (int kt=0; kt<nkt; kt++){
    const bf16* ga = A  + (size_t)(m0+r0)*K + kt*32 + k0;
    const bf16* gb = Bt + (size_t)(n0+r0)*K + kt*32 + k0;
    gload16(ga,                 (char*)&Al[0][0] + tid*16);
    gload16(ga + (size_t)64*K,  (char*)&Al[0][0] + (tid+256)*16);
    gload16(gb,                 (char*)&Bl[0][0] + tid*16);
    gload16(gb + (size_t)64*K,  (char*)&Bl[0][0] + (tid+256)*16);
    __syncthreads();
    int ks = (ln>>4)*8;
    s16x8 af[4], bq[4];
    #pragma unroll
    for (int i=0;i<4;i++){
      af[i] = *(const s16x8*)&Al[wr*64 + i*16 + (ln&15)][ks];
      bq[i] = *(const s16x8*)&Bl[wc*64 + i*16 + (ln&15)][ks];
    }
    #pragma unroll
    for (int mi=0;mi<4;mi++)
      #pragma unroll
      for (int ni=0;ni<4;ni++)
        acc[mi][ni] = __builtin_amdgcn_mfma_f32_16x16x32_bf16(af[mi], bq[ni], acc[mi][ni], 0,0,0);
    __syncthreads();
  }
  #pragma unroll
  for (int mi=0;mi<4;mi++)
    #pragma unroll
    for (int ni=0;ni<4;ni++){
      int col = n0 + wc*64 + ni*16 + (ln&15);
      int rb  = m0 + wr*64 + mi*16 + (ln>>4)*4;
      #pragma unroll
      for (int j=0;j<4;j++){
        size_t idx = (size_t)(rb+j)*N + col;
        float val = acc[mi][ni][j];
        if constexpr(MODE==EP_BF16)           ((bf16*)Out)[idx] = f2bf(val);
        else if constexpr(MODE==EP_TANH_BF16) ((bf16*)Out)[idx] = f2bf(tanhf(val));
        else if constexpr(MODE==EP_RES_F32)   ((float*)Out)[idx] = auxf[idx] + val;
        else if constexpr(MODE==EP_RELU2_BF16){ float m = fmaxf(val,0.f); ((bf16*)Out)[idx] = f2bf(m*m); }
        else if constexpr(MODE==EP_SIG_BF16)  ((bf16*)Out)[idx] = f2bf(1.f/(1.f+expf(-val)));
        else if constexpr(MODE==EP_FINAL_F32) ((float*)Out)[idx] = auxf[idx] + bf2f(auxb[idx])*val;
      }
    }
}

// ---------------- small-N GEMM (used for W1 N=64 and W2 K=64) -------------
template<int MODE>
__global__ __launch_bounds__(256) void gemm_bf16(
    const bf16* __restrict__ A, const bf16* __restrict__ Bt, void* __restrict__ Out,
    int N, int K, const float* __restrict__ bias)
{
  __shared__ bf16 Al[128][40];
  __shared__ bf16 Bl[64][40];
  int tid = threadIdx.x;
  int m0 = blockIdx.x*128, n0 = blockIdx.y*64;
  int wv = tid>>6, ln = tid&63;
  f32x4 acc[2][4];
  #pragma unroll
  for(int f=0;f<2;f++) for(int c=0;c<4;c++){ f32x4 z = {0.f,0.f,0.f,0.f}; acc[f][c]=z; }
  const int nkt = K>>5;
  for (int kt=0; kt<nkt; kt++){
    __syncthreads();
    {
      int c0 = tid, c1 = tid+256;
      int r = c0>>2, ko=(c0&3)*8;
      *(uint4*)&Al[r][ko] = *(const uint4*)&A[(size_t)(m0+r)*K + kt*32 + ko];
      r = c1>>2; ko=(c1&3)*8;
      *(uint4*)&Al[r][ko] = *(const uint4*)&A[(size_t)(m0+r)*K + kt*32 + ko];
      r = tid>>2; ko=(tid&3)*8;
      *(uint4*)&Bl[r][ko] = *(const uint4*)&Bt[(size_t)(n0+r)*K + kt*32 + ko];
    }
    __syncthreads();
    int ks = (ln>>4)*8;
    s16x8 af0 = *(const s16x8*)&Al[wv*32 + (ln&15)][ks];
    s16x8 af1 = *(const s16x8*)&Al[wv*32 + 16 + (ln&15)][ks];
    #pragma unroll
    for (int c=0;c<4;c++){
      s16x8 bfr = *(const s16x8*)&Bl[c*16 + (ln&15)][ks];
      acc[0][c] = __builtin_amdgcn_mfma_f32_16x16x32_bf16(af0, bfr, acc[0][c], 0,0,0);
      acc[1][c] = __builtin_amdgcn_mfma_f32_16x16x32_bf16(af1, bfr, acc[1][c], 0,0,0);
    }
  }
  #pragma unroll
  for (int f=0; f<2; f++) for (int c=0;c<4;c++){
    int col = n0 + c*16 + (ln&15);
    int rbase = m0 + wv*32 + f*16 + (ln>>4)*4;
    #pragma unroll
    for (int j=0;j<4;j++){
      size_t idx = (size_t)(rbase+j)*N + col;
      float val = acc[f][c][j];
      if constexpr(MODE==EP_TANH_BF16)      ((bf16*)Out)[idx] = f2bf(tanhf(val));
      else if constexpr(MODE==EP_NEGEXP_F16){
        float w = fmaxf(-expf(val + bias[col]), -20.f);
        ((f16*)Out)[idx] = (f16)expf(w);
      }
    }
  }
}

// ---------------- WKV6 segment scan (64-token chunks, NSUB=64) ----------------
// P1: 2 waves/block; wave owns 64 v-cols; lane = k. ew read as f16; Dseg = product of factors.
__global__ __launch_bounds__(128,3) void wkv_p1(const bf16* __restrict__ kbuf, const bf16* __restrict__ vbuf,
      const f16* __restrict__ ewb, bf16* __restrict__ Mseg, float* __restrict__ Dseg){
  int bhs = blockIdx.x; int bh = bhs>>6, sub = bhs&63;
  int b = bh>>2, h = bh&3;
  int tid = threadIdx.x, wv = tid>>6, ln = tid&63;
  __shared__ float vtile[16][132];
  int t0 = sub*SUB;
  size_t kqbase = ((size_t)b*TT + t0)*KD + h*64 + ln;
  float dacc = 1.f;
  f32x2 S2[32];
  #pragma unroll
  for (int p=0;p<32;p++){ f32x2 z={0.f,0.f}; S2[p]=z; }
  float wnxt = (float)ewb[kqbase];
  unsigned short qnxt = ((const unsigned short*)kbuf)[kqbase];
  #pragma unroll 1
  for (int tile=0; tile<4; tile++){
    int tb = t0 + tile*16;
    __syncthreads();
    {
      int t = tid>>3, c = (tid&7)*16;
      const unsigned short* vg = (const unsigned short*)vbuf + ((size_t)b*TT + tb + t)*VD + h*128 + c;
      u16x8 a8 = *(const u16x8*)vg;
      u16x8 b8 = *(const u16x8*)(vg+8);
      #pragma unroll
      for (int e=0;e<8;e++){ vtile[t][c+e] = bfbits(a8[e]); vtile[t][c+8+e] = bfbits(b8[e]); }
    }
    __syncthreads();
    #pragma unroll 1
    for (int tt=0;tt<16;tt++){
      int lt = tile*16+tt;
      float e = wnxt; unsigned short qcur = qnxt;
      if (lt < SUB-1){
        size_t gi = kqbase + (size_t)(lt+1)*KD;
        wnxt = (float)ewb[gi]; qnxt = ((const unsigned short*)kbuf)[gi];
      }
      dacc *= e;
      float qv = bfbits(qcur);
      f32x2 e2 = {e,e}, q2 = {qv,qv};
      #pragma unroll
      for (int vg=0;vg<16;vg++){
        f32x4 vvv = *(const f32x4*)&vtile[tt][wv*64 + vg*4];
        f32x2 vA = {vvv[0], vvv[1]}, vB = {vvv[2], vvv[3]};
        S2[vg*2]   = e2*S2[vg*2]   + q2*vA;
        S2[vg*2+1] = e2*S2[vg*2+1] + q2*vB;
      }
    }
  }
  unsigned short* M = (unsigned short*)Mseg + (size_t)bhs*8192 + (size_t)ln*128 + wv*64;
  #pragma unroll
  for (int vg=0; vg<16; vg++){
    ushort4 s4;
    s4.x = f2bfbits(S2[vg*2][0]);   s4.y = f2bfbits(S2[vg*2][1]);
    s4.z = f2bfbits(S2[vg*2+1][0]); s4.w = f2bfbits(S2[vg*2+1][1]);
    *(ushort4*)&M[vg*4] = s4;
  }
  if (wv==0) Dseg[(size_t)bhs*64 + ln] = dacc;
}

// P2: sequential combine across sub-chunks, IN-PLACE bf16 (Mseg becomes Sstart)
__global__ __launch_bounds__(256) void wkv_p2(bf16* __restrict__ MS, const float* __restrict__ Dseg){
  int idx = blockIdx.x*256 + threadIdx.x;
  int bh = idx>>13; int k = (idx>>7)&63; int v = idx&127;
  bf16* p = MS + (size_t)bh*NSUB*8192 + k*128 + v;
  const float* d = Dseg + (size_t)bh*NSUB*64 + k;
  float S = 0.f;
  float m = bf2f(p[0]); float D = d[0];
  #pragma unroll 1
  for (int seg=0; seg<NSUB; seg++){
    float mN=0.f, DN=0.f;
    if (seg < NSUB-1){ mN = bf2f(p[(size_t)(seg+1)*8192]); DN = d[(seg+1)*64]; }
    p[(size_t)seg*8192] = f2bf(S);
    S = D*S + m;
    m = mN; D = DN;
  }
}

// P3: v-lane layout, f32x2-packed fully-unrolled k loop; ew staged from f16 buffer.
__global__ __launch_bounds__(128,3) void wkv_p3(const bf16* __restrict__ rbuf, const bf16* __restrict__ kbuf,
     const bf16* __restrict__ vbuf, const f16* __restrict__ ewb, const bf16* __restrict__ Sstart,
     const float* __restrict__ uu, const bf16* __restrict__ gg,
     const float* __restrict__ gn_w, const float* __restrict__ gn_b, bf16* __restrict__ gated){
  int bhs = blockIdx.x; int bh = bhs>>6, sub = bhs&63;
  int b = bh>>2, h = bh&3;
  int tid = threadIdx.x;
  __shared__ float ew[8][68], qk[8][68], rr[8][68], bu[8];
  __shared__ unsigned short vtb[8][128];
  __shared__ float ot[8][132];
  int tq = tid>>4, cq4 = (tid&15)*4, cq8 = (tid&15)*8;
  float4 u4 = *(const float4*)&uu[h*64 + cq4];
  f32x2 S2[32];
  const unsigned short* Sst = (const unsigned short*)Sstart + (size_t)bhs*8192;
  #pragma unroll
  for (int p=0;p<32;p++){
    f32x2 s = { bfbits(Sst[(2*p)*128 + tid]), bfbits(Sst[(2*p+1)*128 + tid]) };
    S2[p] = s;
  }
  int t0 = sub*SUB;
  #pragma unroll 1
  for (int tile=0; tile<8; tile++){
    int tb = t0 + tile*8;
    // ---- stage 8 tokens of e/q/r/bu/v ----
    {
      size_t gi = ((size_t)b*TT + tb + tq)*KD + h*64 + cq4;
      ushort4 e4s = *(const ushort4*)&((const unsigned short*)ewb)[gi];
      ew[tq][cq4+0]=h2f(e4s.x); ew[tq][cq4+1]=h2f(e4s.y); ew[tq][cq4+2]=h2f(e4s.z); ew[tq][cq4+3]=h2f(e4s.w);
      ushort4 k4 = *(const ushort4*)&((const unsigned short*)kbuf)[gi];
      ushort4 r4 = *(const ushort4*)&((const unsigned short*)rbuf)[gi];
      float q0=bfbits(k4.x),q1=bfbits(k4.y),q2=bfbits(k4.z),q3=bfbits(k4.w);
      float rv0=bfbits(r4.x),rv1=bfbits(r4.y),rv2=bfbits(r4.z),rv3=bfbits(r4.w);
      qk[tq][cq4+0]=q0; qk[tq][cq4+1]=q1; qk[tq][cq4+2]=q2; qk[tq][cq4+3]=q3;
      rr[tq][cq4+0]=rv0; rr[tq][cq4+1]=rv1; rr[tq][cq4+2]=rv2; rr[tq][cq4+3]=rv3;
      float part = rv0*q0*u4.x + rv1*q1*u4.y + rv2*q2*u4.z + rv3*q3*u4.w;
      part += __shfl_xor(part,1,64); part += __shfl_xor(part,2,64);
      part += __shfl_xor(part,4,64); part += __shfl_xor(part,8,64);
      if ((tid&15)==0) bu[tq] = part;
      *(u16x8*)&vtb[tq][cq8] = *(const u16x8*)&((const unsigned short*)vbuf)[((size_t)b*TT + tb + tq)*VD + h*128 + cq8];
    }
    __syncthreads();
    // ---- scan 8 tokens; o lane-local; packed k loop fully unrolled ----
    #pragma unroll 1
    for (int t=0;t<8;t++){
      float vl = bfbits(vtb[t][tid]);
      f32x2 vl2 = {vl, vl};
      f32x2 o2 = {0.f, 0.f};
      #pragma unroll
      for (int g=0;g<16;g++){
        f32x4 e4 = *(const f32x4*)&ew[t][g*4];
        f32x4 q4 = *(const f32x4*)&qk[t][g*4];
        f32x4 r4 = *(const f32x4*)&rr[t][g*4];
        f32x2 eA = {e4[0],e4[1]}, eB = {e4[2],e4[3]};
        f32x2 qA = {q4[0],q4[1]}, qB = {q4[2],q4[3]};
        f32x2 rA = {r4[0],r4[1]}, rB = {r4[2],r4[3]};
        int p = g*2;
        o2 += rA*S2[p];   S2[p]   = eA*S2[p]   + qA*vl2;
        o2 += rB*S2[p+1]; S2[p+1] = eB*S2[p+1] + qB*vl2;
      }
      float o = o2[0] + o2[1] + bu[t]*vl;
      ot[t][tid] = o;
    }
    __syncthreads();
    // ---- GN + silu gate: thread handles token tq, channels cq8..cq8+7 ----
    {
      float gw[8], gb[8];
      *(float4*)&gw[0] = *(const float4*)&gn_w[h*128+cq8];
      *(float4*)&gw[4] = *(const float4*)&gn_w[h*128+cq8+4];
      *(float4*)&gb[0] = *(const float4*)&gn_b[h*128+cq8];
      *(float4*)&gb[4] = *(const float4*)&gn_b[h*128+cq8+4];
      float o8[8];
      *(float4*)&o8[0] = *(const float4*)&ot[tq][cq8];
      *(float4*)&o8[4] = *(const float4*)&ot[tq][cq8+4];
      float s = 0.f, ss = 0.f;
      #pragma unroll
      for (int e=0;e<8;e++){ s += o8[e]; ss += o8[e]*o8[e]; }
      s += __shfl_xor(s,1,64); ss += __shfl_xor(ss,1,64);
      s += __shfl_xor(s,2,64); ss += __shfl_xor(ss,2,64);
      s += __shfl_xor(s,4,64); ss += __shfl_xor(ss,4,64);
      s += __shfl_xor(s,8,64); ss += __shfl_xor(ss,8,64);
      float mu = s*(1.f/128.f);
      float inv = rsqrtf(fmaxf(ss*(1.f/128.f) - mu*mu, 0.f) + 1e-5f);
      size_t go = ((size_t)b*TT + tb + tq)*VD + h*128 + cq8;
      u16x8 g8 = *(const u16x8*)&((const unsigned short*)gg)[go];
      u16x8 out8;
      #pragma unroll
      for (int e=0;e<8;e++){
        float xv = (o8[e]-mu)*inv*gw[e] + gb[e];
        float ga = bfbits(g8[e]);
        xv *= ga/(1.f+expf(-ga));
        out8[e] = f2bfbits(xv);
      }
      *(u16x8*)&((unsigned short*)gated)[go] = out8;
    }
    __syncthreads();
  }
}

// ---------------- FFN lerp inputs (bf16, 8 elems/thread) ----------------
__global__ void build_ffn_in(const bf16* __restrict__ hn, const float* __restrict__ mu_k,
                             const float* __restrict__ mu_r, bf16* __restrict__ kin, bf16* __restrict__ rin){
  size_t base = ((size_t)blockIdx.x*256 + threadIdx.x)*8;
  int c = (int)(base & (CC-1));
  size_t bt = base >> 9;
  u16x8 hv8 = *(const u16x8*)&((const unsigned short*)hn)[base];
  u16x8 hp8;
  if (bt & (TT-1)) hp8 = *(const u16x8*)&((const unsigned short*)hn)[base - CC];
  else { hp8 = u16x8{0,0,0,0,0,0,0,0}; }
  float mk8[8], mr8[8];
  *(float4*)&mk8[0] = *(const float4*)&mu_k[c];
  *(float4*)&mk8[4] = *(const float4*)&mu_k[c+4];
  *(float4*)&mr8[0] = *(const float4*)&mu_r[c];
  *(float4*)&mr8[4] = *(const float4*)&mu_r[c+4];
  u16x8 k8, r8;
  #pragma unroll
  for (int e=0;e<8;e++){
    float f = bfbits(hv8[e]), p = bfbits(hp8[e]);
    float d = p - f;
    k8[e] = f2bfbits(f + d*mk8[e]);
    r8[e] = f2bfbits(f + d*mr8[e]);
  }
  *(u16x8*)&((unsigned short*)kin)[base] = k8;
  *(u16x8*)&((unsigned short*)rin)[base] = r8;
}

extern "C" void kernel_launch(void* const* d_in, const int* in_sizes, int n_in,
                              void* d_out, int out_size, void* d_ws, size_t ws_size,
                              hipStream_t stream){
  (void)in_sizes; (void)n_in; (void)out_size;
  if (ws_size < WS_NEED) return;
  const float* x      = (const float*)d_in[0];
  const float* ln1w   = (const float*)d_in[1];
  const float* ln1b   = (const float*)d_in[2];
  const float* mu_x   = (const float*)d_in[3];
  const float* W_x1   = (const float*)d_in[4];
  const float* W_x2   = (const float*)d_in[5];
  const float* x_bias = (const float*)d_in[6];
  const float* W_r    = (const float*)d_in[7];
  const float* W_k    = (const float*)d_in[8];
  const float* W_v    = (const float*)d_in[9];
  const float* W_g    = (const float*)d_in[10];
  const float* W_w1   = (const float*)d_in[11];
  const float* W_w2   = (const float*)d_in[12];
  const float* b_w2   = (const float*)d_in[13];
  const float* u      = (const float*)d_in[14];
  const float* gn_w   = (const float*)d_in[15];
  const float* gn_b   = (const float*)d_in[16];
  const float* W_o    = (const float*)d_in[17];
  const float* ln2w   = (const float*)d_in[18];
  const float* ln2b   = (const float*)d_in[19];
  const float* mu_k   = (const float*)d_in[20];
  const float* W_key  = (const float*)d_in[21];
  const float* mu_r   = (const float*)d_in[22];
  const float* W_rec  = (const float*)d_in[23];
  const float* W_val  = (const float*)d_in[24];
  char* ws = (char*)d_ws;
  auto F  = [&](size_t off){ return (float*)(ws+off); };
  auto Bf = [&](size_t off){ return (bf16*)(ws+off); };
  float* h2 = (float*)d_out;        // attn-out residual lives in d_out
  bf16* Mseg = (bf16*)d_out;        // scan summaries alias d_out (dead before O-gemm)

  // tiled weight conversions (620 blocks, coalesced)
  wconv_t2<<<620,256,0,stream>>>(W_x1,W_r,W_k,W_v,W_g,W_w1,W_w2,W_o,W_key,W_rec,W_val, ws);

  // ---- attention pre-projections ----
  ln_bf16<<<BT,256,0,stream>>>(x, ln1w, ln1b, Bf(OFF_H1));
  build_xm<<<BT*CC/8/256,256,0,stream>>>(Bf(OFF_H1), mu_x, Bf(OFF_HM));
  gemm128<EP_TANH_BF16><<<512,256,0,stream>>>(Bf(OFF_HM), Bf(WT_X1), Bf(OFF_XX), 256,512, nullptr,nullptr);

  // fused 5-way hm build: hm0->HM, hm1->dout[0:32M], hm2->dout[32M:64M], hm3->G region, hm4->WD region
  bf16* hm1 = (bf16*)d_out;
  bf16* hm2 = (bf16*)((char*)d_out + 32*MiB);
  build_hm5<<<dim3(BT/16,4),128,0,stream>>>(Bf(OFF_H1), Bf(OFF_XX), W_x2, x_bias,
                                            Bf(OFF_HM), hm1, hm2, Bf(OFF_G), Bf(OFF_WD));
  // projections (order keeps region lifetimes disjoint)
  gemm128<EP_BF16><<<512,256,0,stream>>>(Bf(OFF_HM), Bf(WT_R), Bf(OFF_R), 256,512, nullptr,nullptr);
  gemm_bf16<EP_TANH_BF16><<<dim3(BT/128,1),256,0,stream>>>(hm1, Bf(WT_W1), Bf(OFF_W1T), 64,512, nullptr);
  gemm128<EP_BF16><<<512,256,0,stream>>>(hm2, Bf(WT_K), Bf(OFF_K), 256,512, nullptr,nullptr);
  gemm128<EP_BF16><<<1024,256,0,stream>>>(Bf(OFF_G), Bf(WT_V), Bf(OFF_V), 512,512, nullptr,nullptr);
  gemm128<EP_BF16><<<1024,256,0,stream>>>(Bf(OFF_WD), Bf(WT_G), Bf(OFF_G), 512,512, nullptr,nullptr);
  gemm_bf16<EP_NEGEXP_F16><<<dim3(BT/128,4),256,0,stream>>>(Bf(OFF_W1T), Bf(WT_W2), (void*)F(OFF_WD), 256,64, b_w2);

  // ---- WKV6 segment scan (SUB=64, NSUB=64); Mseg/Sstart in d_out ----
  wkv_p1<<<BB*4*NSUB,128,0,stream>>>(Bf(OFF_K), Bf(OFF_V), (const f16*)F(OFF_WD), Mseg, F(OFF_DSEG));
  wkv_p2<<<BB*4*8192/256,256,0,stream>>>(Mseg, F(OFF_DSEG));
  wkv_p3<<<BB*4*NSUB,128,0,stream>>>(Bf(OFF_R), Bf(OFF_K), Bf(OFF_V), (const f16*)F(OFF_WD), Mseg, u,
                                     Bf(OFF_G), gn_w, gn_b, Bf(OFF_H1));

  // ---- output projection + residual -> h2 (in d_out; overwrites Mseg) ----
  gemm128<EP_RES_F32><<<1024,256,0,stream>>>(Bf(OFF_H1), Bf(WT_O), h2, 512,512, x,nullptr);

  // ---- channel mixing (FFN) ----
  ln_bf16<<<BT,256,0,stream>>>(h2, ln2w, ln2b, Bf(OFF_HM));
  build_ffn_in<<<BT*CC/8/256,256,0,stream>>>(Bf(OFF_HM), mu_k, mu_r, Bf(OFF_R), Bf(OFF_V));
  gemm128<EP_RELU2_BF16><<<2048,256,0,stream>>>(Bf(OFF_R), Bf(WT_KEY), Bf(OFF_WD), 1024,512, nullptr,nullptr);
  gemm128<EP_SIG_BF16><<<1024,256,0,stream>>>(Bf(OFF_V), Bf(WT_REC), Bf(OFF_H1), 512,512, nullptr,nullptr);
  gemm128<EP_FINAL_F32><<<1024,256,0,stream>>>(Bf(OFF_WD), Bf(WT_VAL), h2, 512,1024, h2, Bf(OFF_H1));
}

// Round 10
// 846.373 us; speedup vs baseline: 2.6673x; 1.1119x over previous
//
#include <hip/hip_runtime.h>
#include <hip/hip_bf16.h>
#include <hip/hip_fp16.h>
#include <math.h>

#define BB 8
#define TT 4096
#define CC 512
#define BT (BB*TT)
#define KD 256
#define VD 512
#define NSUB 64
#define SUB 64

using bf16 = __hip_bfloat16;
using f16 = _Float16;
typedef __attribute__((ext_vector_type(2))) float f32x2;
typedef __attribute__((ext_vector_type(4))) float f32x4;
typedef __attribute__((ext_vector_type(8))) short s16x8;
typedef __attribute__((ext_vector_type(8))) unsigned short u16x8;
typedef const __attribute__((address_space(1))) unsigned int gu32;
typedef __attribute__((address_space(3))) unsigned int lu32;

static __device__ __forceinline__ float bf2f(bf16 x){ return __bfloat162float(x); }
static __device__ __forceinline__ bf16 f2bf(float x){ return __float2bfloat16(x); }
static __device__ __forceinline__ float bfbits(unsigned short u){
  union { unsigned int i; float f; } x; x.i = ((unsigned int)u)<<16; return x.f;
}
static __device__ __forceinline__ unsigned short f2bfbits(float f){
  union { bf16 b; unsigned short u; } x; x.b = f2bf(f); return x.u;
}
static __device__ __forceinline__ float h2f(unsigned short u){
  f16 h; __builtin_memcpy(&h,&u,2); return (float)h;
}
static __device__ __forceinline__ void gload16(const void* g, void* l){
  __builtin_amdgcn_global_load_lds((gu32*)g, (lu32*)l, 16, 0, 0);
}

// ---------------- workspace arena (bytes); Mseg lives in d_out ----------------
#define MiB 1048576ull
static constexpr size_t OFF_H1   = 0;           // bf16 BT*C (32)  ; p3 out GATED ; FFN RF
static constexpr size_t OFF_XX   = 32*MiB;      // bf16 BT*256 (16); dead by scan
static constexpr size_t OFF_DSEG = 32*MiB;      // f32 2048*64 (0.5) alias XX
static constexpr size_t OFF_HM   = 48*MiB;      // bf16 BT*C (32) = hm0 ; FFN HN
static constexpr size_t OFF_R    = 80*MiB;      // bf16 BT*256 (16); FFN KIN (spans R+K)
static constexpr size_t OFF_K    = 96*MiB;      // bf16 BT*256 (16)
static constexpr size_t OFF_V    = 112*MiB;     // bf16 BT*512 (32); FFN RIN
static constexpr size_t OFF_WD   = 144*MiB;     // f16 BT*256 (16) ew; build: hm4 (32); FFN KF low
static constexpr size_t OFF_G    = 176*MiB;     // bf16 BT*512 (32) g; build: hm3 ; FFN KF high
static constexpr size_t OFF_W1T  = 208*MiB;     // bf16 BT*64 (4)
static constexpr size_t WT_X1  = 212*MiB;            // 512x256 bf16
static constexpr size_t WT_R   = WT_X1  + 262144;
static constexpr size_t WT_K   = WT_R   + 262144;
static constexpr size_t WT_V   = WT_K   + 262144;
static constexpr size_t WT_G   = WT_V   + 524288;
static constexpr size_t WT_W1  = WT_G   + 524288;
static constexpr size_t WT_W2  = WT_W1  + 65536;
static constexpr size_t WT_O   = WT_W2  + 32768;
static constexpr size_t WT_KEY = WT_O   + 524288;
static constexpr size_t WT_REC = WT_KEY + 1048576;
static constexpr size_t WT_VAL = WT_REC + 524288;
static constexpr size_t WT_X2T = WT_VAL + 1048576;   // bf16 [5][512][32]
static constexpr size_t WS_NEED = WT_X2T + 163840;

// ---------------- tiled transposed weight convert (coalesced both sides) ----------------
__global__ __launch_bounds__(256) void wconv_t2(const float* s0, const float* s1, const float* s2,
        const float* s3, const float* s4, const float* s5, const float* s6, const float* s7,
        const float* s8, const float* s9, const float* s10, char* ws){
  struct E{int K,N,Npad; size_t off;};
  const E tab[11] = {
    {512,160,256,WT_X1},{512,256,256,WT_R},{512,256,256,WT_K},{512,512,512,WT_V},
    {512,512,512,WT_G},{512,64,64,WT_W1},{64,256,256,WT_W2},{512,512,512,WT_O},
    {512,1024,1024,WT_KEY},{512,512,512,WT_REC},{1024,512,512,WT_VAL}};
  const float* srcs[11] = {s0,s1,s2,s3,s4,s5,s6,s7,s8,s9,s10};
  int blk = blockIdx.x, i = 0, acc = 0;
  #pragma unroll 1
  for (; i<11; i++){ int nt = (tab[i].K>>6)*(tab[i].Npad>>6); if (blk < acc+nt) break; acc += nt; }
  int local = blk - acc;
  int K = tab[i].K, N = tab[i].N;
  int ntn = tab[i].Npad>>6;
  int k0 = (local/ntn)*64, n0 = (local%ntn)*64;
  const float* src = srcs[i];
  bf16* dst = (bf16*)(ws + tab[i].off);
  __shared__ float T[64][65];
  int t = threadIdx.x;
  #pragma unroll
  for (int e=0;e<16;e++){
    int idx = t + e*256; int r = idx>>6, c = idx&63;
    int n = n0 + c;
    T[r][c] = (n < N) ? src[(size_t)(k0+r)*N + n] : 0.f;
  }
  __syncthreads();
  #pragma unroll
  for (int e=0;e<16;e++){
    int idx = t + e*256; int r = idx>>6, c = idx&63;
    dst[(size_t)(n0+r)*K + k0 + c] = f2bf(T[c][r]);
  }
}

// ---------------- W_x2 -> bf16 [5][512][32] transposed (tiny) ----------------
__global__ void wconv_x2(const float* __restrict__ src, bf16* __restrict__ dst){
  int idx = blockIdx.x*256 + threadIdx.x;   // 81920 total
  int i = idx >> 14;
  int rem = idx & 16383;
  int c = rem >> 5, r = rem & 31;
  dst[idx] = f2bf(src[((size_t)i*32 + r)*512 + c]);
}

// ---------------- LayerNorm over C=512, block per row, bf16 out ----------------
__global__ __launch_bounds__(256) void ln_bf16(const float* __restrict__ x, const float* __restrict__ w,
                                               const float* __restrict__ b, bf16* __restrict__ out){
  int bt = blockIdx.x;
  const float* row = x + (size_t)bt*CC;
  int t = threadIdx.x;
  float a0 = row[t], a1 = row[t+256];
  float s = a0 + a1, ss = a0*a0 + a1*a1;
  for (int off=32; off; off>>=1){ s += __shfl_down(s, off, 64); ss += __shfl_down(ss, off, 64); }
  __shared__ float ps[4], pss[4];
  int wv = t>>6, ln = t&63;
  if (ln==0){ ps[wv]=s; pss[wv]=ss; }
  __syncthreads();
  if (t==0){
    float S=ps[0]+ps[1]+ps[2]+ps[3], SS=pss[0]+pss[1]+pss[2]+pss[3];
    float mu = S/CC; float var = SS/CC - mu*mu;
    ps[0]=mu; pss[0]=rsqrtf(var+1e-5f);
  }
  __syncthreads();
  float mu = ps[0], inv = pss[0];
  out[(size_t)bt*CC + t]     = f2bf((a0-mu)*inv*w[t]+b[t]);
  out[(size_t)bt*CC + t+256] = f2bf((a1-mu)*inv*w[t+256]+b[t+256]);
}

// ---------------- xm = h + (shift(h)-h)*mu_x  (bf16, 8 elems/thread) ----------------
__global__ void build_xm(const bf16* __restrict__ h, const float* __restrict__ mu_x, bf16* __restrict__ xm){
  size_t base = ((size_t)blockIdx.x*256 + threadIdx.x)*8;
  int c = (int)(base & (CC-1));
  size_t bt = base >> 9;
  u16x8 hv8 = *(const u16x8*)&((const unsigned short*)h)[base];
  u16x8 hp8;
  if (bt & (TT-1)) hp8 = *(const u16x8*)&((const unsigned short*)h)[base - CC];
  else { hp8 = u16x8{0,0,0,0,0,0,0,0}; }
  float m8[8];
  *(float4*)&m8[0] = *(const float4*)&mu_x[c];
  *(float4*)&m8[4] = *(const float4*)&mu_x[c+4];
  u16x8 o8;
  #pragma unroll
  for (int e=0;e<8;e++){
    float f = bfbits(hv8[e]), p = bfbits(hp8[e]);
    o8[e] = f2bfbits(f + (p-f)*m8[e]);
  }
  *(u16x8*)&((unsigned short*)xm)[base] = o8;
}

// ---------------- MFMA-fused 5-way lerp-mix build ----------------
// Block: 128 tokens x 128 channels. Operands swapped (A=W channels, B=xx tokens) so each lane
// holds 4 consecutive CHANNELS of one token -> vectorized ushort4 epilogue loads/stores.
__global__ __launch_bounds__(256) void hm5_mfma(const bf16* __restrict__ h, const bf16* __restrict__ xx,
      const bf16* __restrict__ wx2t, const float* __restrict__ x_bias,
      bf16* __restrict__ hm0, bf16* __restrict__ hm1, bf16* __restrict__ hm2,
      bf16* __restrict__ hm3, bf16* __restrict__ hm4){
  __shared__ bf16 xxl[128][168];
  int bt0 = blockIdx.x*128;
  int c0 = blockIdx.y*128;
  int tid = threadIdx.x;
  #pragma unroll
  for (int p=0;p<10;p++){
    int idx = p*256 + tid;
    int row = idx/20, q = idx - row*20;
    *(uint4*)&xxl[row][q*8] = *(const uint4*)&xx[((size_t)(bt0+row))*256 + q*8];
  }
  __syncthreads();
  int wv = tid>>6, ln = tid&63;
  int wr = wv>>1, wc = wv&1;          // wr: channel half, wc: token half
  int ks = (ln>>4)*8;
  int l15 = ln&15;
  bf16* const outs[5] = {hm0,hm1,hm2,hm3,hm4};
  #pragma unroll
  for (int i=0;i<5;i++){
    // B-frags: xx tokens (from LDS)
    s16x8 bq[4];
    #pragma unroll
    for (int ni=0;ni<4;ni++)
      bq[ni] = *(const s16x8*)&xxl[wc*64 + ni*16 + l15][i*32 + ks];
    // accumulators init = bias (channel-dependent, token-independent)
    f32x4 acc[4][4];
    #pragma unroll
    for (int mi=0;mi<4;mi++){
      int chb = c0 + wr*64 + mi*16 + (ln>>4)*4;
      float4 bia = *(const float4*)&x_bias[i*CC + chb];
      #pragma unroll
      for (int ni=0;ni<4;ni++){ f32x4 a = {bia.x,bia.y,bia.z,bia.w}; acc[mi][ni] = a; }
    }
    // MFMA: A = W channels (from global, L1-hot)
    #pragma unroll
    for (int mi=0;mi<4;mi++){
      s16x8 aw = *(const s16x8*)&wx2t[((size_t)i*512 + c0 + wr*64 + mi*16 + l15)*32 + ks];
      #pragma unroll
      for (int ni=0;ni<4;ni++)
        acc[mi][ni] = __builtin_amdgcn_mfma_f32_16x16x32_bf16(aw, bq[ni], acc[mi][ni], 0,0,0);
    }
    // epilogue: lerp + store (4 consecutive channels per lane)
    bf16* o = outs[i];
    #pragma unroll
    for (int mi=0;mi<4;mi++){
      int ch = c0 + wr*64 + mi*16 + (ln>>4)*4;
      #pragma unroll
      for (int ni=0;ni<4;ni++){
        int tok = bt0 + wc*64 + ni*16 + l15;
        size_t base = (size_t)tok*CC + ch;
        ushort4 hv4 = *(const ushort4*)&((const unsigned short*)h)[base];
        ushort4 hp4;
        if (tok & (TT-1)) hp4 = *(const ushort4*)&((const unsigned short*)h)[base - CC];
        else { hp4.x=0; hp4.y=0; hp4.z=0; hp4.w=0; }
        ushort4 o4;
        float hv, hp, mus;
        hv = bfbits(hv4.x); hp = bfbits(hp4.x); mus = acc[mi][ni][0]; o4.x = f2bfbits(hv + (hp-hv)*mus);
        hv = bfbits(hv4.y); hp = bfbits(hp4.y); mus = acc[mi][ni][1]; o4.y = f2bfbits(hv + (hp-hv)*mus);
        hv = bfbits(hv4.z); hp = bfbits(hp4.z); mus = acc[mi][ni][2]; o4.z = f2bfbits(hv + (hp-hv)*mus);
        hv = bfbits(hv4.w); hp = bfbits(hp4.w); mus = acc[mi][ni][3]; o4.w = f2bfbits(hv + (hp-hv)*mus);
        *(ushort4*)&((unsigned short*)o)[base] = o4;
      }
    }
  }
}

// ---------------- epilogue modes ----------------
enum {EP_BF16, EP_TANH_BF16, EP_NEGEXP_F16, EP_RES_F32, EP_RELU2_BF16, EP_SIG_BF16, EP_FINAL_F32};

// ---------------- m97-style 128x128 MFMA GEMM with global_load_lds staging -------------
template<int MODE>
__global__ __launch_bounds__(256) void gemm128(
    const bf16* __restrict__ A, const bf16* __restrict__ Bt, void* __restrict__ Out,
    int N, int K, const float* __restrict__ auxf, const bf16* __restrict__ auxb)
{
  __shared__ bf16 Al[128][32];
  __shared__ bf16 Bl[128][32];
  int tid = threadIdx.x;
  int nbk = N>>7;
  int q8 = gridDim.x>>3;
  int o = (blockIdx.x & 7)*q8 + (blockIdx.x>>3);
  int nb = o % nbk, mb = o / nbk;
  int m0 = mb*128, n0 = nb*128;
  int wv = tid>>6, ln = tid&63;
  int wr = wv>>1, wc = wv&1;
  f32x4 acc[4][4];
  #pragma unroll
  for (int i=0;i<4;i++) for (int j=0;j<4;j++){ f32x4 z={0.f,0.f,0.f,0.f}; acc[i][j]=z; }
  int r0 = tid>>2, k0 = (tid&3)*8;
  const int nkt = K>>5;
  for (int kt=0; kt<nkt; kt++){
    const bf16* ga = A  + (size_t)(m0+r0)*K + kt*32 + k0;
    const bf16* gb = Bt + (size_t)(n0+r0)*K + kt*32 + k0;
    gload16(ga,                 (char*)&Al[0][0] + tid*16);
    gload16(ga + (size_t)64*K,  (char*)&Al[0][0] + (tid+256)*16);
    gload16(gb,                 (char*)&Bl[0][0] + tid*16);
    gload16(gb + (size_t)64*K,  (char*)&Bl[0][0] + (tid+256)*16);
    __syncthreads();
    int ks = (ln>>4)*8;
    s16x8 af[4], bq[4];
    #pragma unroll
    for (int i=0;i<4;i++){
      af[i] = *(const s16x8*)&Al[wr*64 + i*16 + (ln&15)][ks];
      bq[i] = *(const s16x8*)&Bl[wc*64 + i*16 + (ln&15)][ks];
    }
    #pragma unroll
    for (int mi=0;mi<4;mi++)
      #pragma unroll
      for (int ni=0;ni<4;ni++)
        acc[mi][ni] = __builtin_amdgcn_mfma_f32_16x16x32_bf16(af[mi], bq[ni], acc[mi][ni], 0,0,0);
    __syncthreads();
  }
  #pragma unroll
  for (int mi=0;mi<4;mi++)
    #pragma unroll
    for (int ni=0;ni<4;ni++){
      int col = n0 + wc*64 + ni*16 + (ln&15);
      int rb  = m0 + wr*64 + mi*16 + (ln>>4)*4;
      #pragma unroll
      for (int j=0;j<4;j++){
        size_t idx = (size_t)(rb+j)*N + col;
        float val = acc[mi][ni][j];
        if constexpr(MODE==EP_BF16)           ((bf16*)Out)[idx] = f2bf(val);
        else if constexpr(MODE==EP_TANH_BF16) ((bf16*)Out)[idx] = f2bf(tanhf(val));
        else if constexpr(MODE==EP_RES_F32)   ((float*)Out)[idx] = auxf[idx] + val;
        else if constexpr(MODE==EP_RELU2_BF16){ float m = fmaxf(val,0.f); ((bf16*)Out)[idx] = f2bf(m*m); }
        else if constexpr(MODE==EP_SIG_BF16)  ((bf16*)Out)[idx] = f2bf(1.f/(1.f+expf(-val)));
        else if constexpr(MODE==EP_FINAL_F32) ((float*)Out)[idx] = auxf[idx] + bf2f(auxb[idx])*val;
      }
    }
}

// ---------------- small-N GEMM (used for W1 N=64 and W2 K=64) -------------
template<int MODE>
__global__ __launch_bounds__(256) void gemm_bf16(
    const bf16* __restrict__ A, const bf16* __restrict__ Bt, void* __restrict__ Out,
    int N, int K, const float* __restrict__ bias)
{
  __shared__ bf16 Al[128][40];
  __shared__ bf16 Bl[64][40];
  int tid = threadIdx.x;
  int m0 = blockIdx.x*128, n0 = blockIdx.y*64;
  int wv = tid>>6, ln = tid&63;
  f32x4 acc[2][4];
  #pragma unroll
  for(int f=0;f<2;f++) for(int c=0;c<4;c++){ f32x4 z = {0.f,0.f,0.f,0.f}; acc[f][c]=z; }
  const int nkt = K>>5;
  for (int kt=0; kt<nkt; kt++){
    __syncthreads();
    {
      int c0 = tid, c1 = tid+256;
      int r = c0>>2, ko=(c0&3)*8;
      *(uint4*)&Al[r][ko] = *(const uint4*)&A[(size_t)(m0+r)*K + kt*32 + ko];
      r = c1>>2; ko=(c1&3)*8;
      *(uint4*)&Al[r][ko] = *(const uint4*)&A[(size_t)(m0+r)*K + kt*32 + ko];
      r = tid>>2; ko=(tid&3)*8;
      *(uint4*)&Bl[r][ko] = *(const uint4*)&Bt[(size_t)(n0+r)*K + kt*32 + ko];
    }
    __syncthreads();
    int ks = (ln>>4)*8;
    s16x8 af0 = *(const s16x8*)&Al[wv*32 + (ln&15)][ks];
    s16x8 af1 = *(const s16x8*)&Al[wv*32 + 16 + (ln&15)][ks];
    #pragma unroll
    for (int c=0;c<4;c++){
      s16x8 bfr = *(const s16x8*)&Bl[c*16 + (ln&15)][ks];
      acc[0][c] = __builtin_amdgcn_mfma_f32_16x16x32_bf16(af0, bfr, acc[0][c], 0,0,0);
      acc[1][c] = __builtin_amdgcn_mfma_f32_16x16x32_bf16(af1, bfr, acc[1][c], 0,0,0);
    }
  }
  #pragma unroll
  for (int f=0; f<2; f++) for (int c=0;c<4;c++){
    int col = n0 + c*16 + (ln&15);
    int rbase = m0 + wv*32 + f*16 + (ln>>4)*4;
    #pragma unroll
    for (int j=0;j<4;j++){
      size_t idx = (size_t)(rbase+j)*N + col;
      float val = acc[f][c][j];
      if constexpr(MODE==EP_TANH_BF16)      ((bf16*)Out)[idx] = f2bf(tanhf(val));
      else if constexpr(MODE==EP_NEGEXP_F16){
        float w = fmaxf(-expf(val + bias[col]), -20.f);
        ((f16*)Out)[idx] = (f16)expf(w);
      }
    }
  }
}

// ---------------- WKV6 segment scan (64-token chunks, NSUB=64) ----------------
__global__ __launch_bounds__(128,3) void wkv_p1(const bf16* __restrict__ kbuf, const bf16* __restrict__ vbuf,
      const f16* __restrict__ ewb, bf16* __restrict__ Mseg, float* __restrict__ Dseg){
  int bhs = blockIdx.x; int bh = bhs>>6, sub = bhs&63;
  int b = bh>>2, h = bh&3;
  int tid = threadIdx.x, wv = tid>>6, ln = tid&63;
  __shared__ float vtile[16][132];
  int t0 = sub*SUB;
  size_t kqbase = ((size_t)b*TT + t0)*KD + h*64 + ln;
  float dacc = 1.f;
  f32x2 S2[32];
  #pragma unroll
  for (int p=0;p<32;p++){ f32x2 z={0.f,0.f}; S2[p]=z; }
  float wnxt = (float)ewb[kqbase];
  unsigned short qnxt = ((const unsigned short*)kbuf)[kqbase];
  #pragma unroll 1
  for (int tile=0; tile<4; tile++){
    int tb = t0 + tile*16;
    __syncthreads();
    {
      int t = tid>>3, c = (tid&7)*16;
      const unsigned short* vg = (const unsigned short*)vbuf + ((size_t)b*TT + tb + t)*VD + h*128 + c;
      u16x8 a8 = *(const u16x8*)vg;
      u16x8 b8 = *(const u16x8*)(vg+8);
      #pragma unroll
      for (int e=0;e<8;e++){ vtile[t][c+e] = bfbits(a8[e]); vtile[t][c+8+e] = bfbits(b8[e]); }
    }
    __syncthreads();
    #pragma unroll 1
    for (int tt=0;tt<16;tt++){
      int lt = tile*16+tt;
      float e = wnxt; unsigned short qcur = qnxt;
      if (lt < SUB-1){
        size_t gi = kqbase + (size_t)(lt+1)*KD;
        wnxt = (float)ewb[gi]; qnxt = ((const unsigned short*)kbuf)[gi];
      }
      dacc *= e;
      float qv = bfbits(qcur);
      f32x2 e2 = {e,e}, q2 = {qv,qv};
      #pragma unroll
      for (int vg=0;vg<16;vg++){
        f32x4 vvv = *(const f32x4*)&vtile[tt][wv*64 + vg*4];
        f32x2 vA = {vvv[0], vvv[1]}, vB = {vvv[2], vvv[3]};
        S2[vg*2]   = e2*S2[vg*2]   + q2*vA;
        S2[vg*2+1] = e2*S2[vg*2+1] + q2*vB;
      }
    }
  }
  unsigned short* M = (unsigned short*)Mseg + (size_t)bhs*8192 + (size_t)ln*128 + wv*64;
  #pragma unroll
  for (int vg=0; vg<16; vg++){
    ushort4 s4;
    s4.x = f2bfbits(S2[vg*2][0]);   s4.y = f2bfbits(S2[vg*2][1]);
    s4.z = f2bfbits(S2[vg*2+1][0]); s4.w = f2bfbits(S2[vg*2+1][1]);
    *(ushort4*)&M[vg*4] = s4;
  }
  if (wv==0) Dseg[(size_t)bhs*64 + ln] = dacc;
}

// P2: sequential combine across sub-chunks, IN-PLACE bf16 (Mseg becomes Sstart)
__global__ __launch_bounds__(256) void wkv_p2(bf16* __restrict__ MS, const float* __restrict__ Dseg){
  int idx = blockIdx.x*256 + threadIdx.x;
  int bh = idx>>13; int k = (idx>>7)&63; int v = idx&127;
  bf16* p = MS + (size_t)bh*NSUB*8192 + k*128 + v;
  const float* d = Dseg + (size_t)bh*NSUB*64 + k;
  float S = 0.f;
  float m = bf2f(p[0]); float D = d[0];
  #pragma unroll 1
  for (int seg=0; seg<NSUB; seg++){
    float mN=0.f, DN=0.f;
    if (seg < NSUB-1){ mN = bf2f(p[(size_t)(seg+1)*8192]); DN = d[(seg+1)*64]; }
    p[(size_t)seg*8192] = f2bf(S);
    S = D*S + m;
    m = mN; D = DN;
  }
}

// P3: v-lane layout, f32x2-packed fully-unrolled k loop; ew staged from f16 buffer.
__global__ __launch_bounds__(128,3) void wkv_p3(const bf16* __restrict__ rbuf, const bf16* __restrict__ kbuf,
     const bf16* __restrict__ vbuf, const f16* __restrict__ ewb, const bf16* __restrict__ Sstart,
     const float* __restrict__ uu, const bf16* __restrict__ gg,
     const float* __restrict__ gn_w, const float* __restrict__ gn_b, bf16* __restrict__ gated){
  int bhs = blockIdx.x; int bh = bhs>>6, sub = bhs&63;
  int b = bh>>2, h = bh&3;
  int tid = threadIdx.x;
  __shared__ float ew[8][68], qk[8][68], rr[8][68], bu[8];
  __shared__ unsigned short vtb[8][128];
  __shared__ float ot[8][132];
  int tq = tid>>4, cq4 = (tid&15)*4, cq8 = (tid&15)*8;
  float4 u4 = *(const float4*)&uu[h*64 + cq4];
  f32x2 S2[32];
  const unsigned short* Sst = (const unsigned short*)Sstart + (size_t)bhs*8192;
  #pragma unroll
  for (int p=0;p<32;p++){
    f32x2 s = { bfbits(Sst[(2*p)*128 + tid]), bfbits(Sst[(2*p+1)*128 + tid]) };
    S2[p] = s;
  }
  int t0 = sub*SUB;
  #pragma unroll 1
  for (int tile=0; tile<8; tile++){
    int tb = t0 + tile*8;
    {
      size_t gi = ((size_t)b*TT + tb + tq)*KD + h*64 + cq4;
      ushort4 e4s = *(const ushort4*)&((const unsigned short*)ewb)[gi];
      ew[tq][cq4+0]=h2f(e4s.x); ew[tq][cq4+1]=h2f(e4s.y); ew[tq][cq4+2]=h2f(e4s.z); ew[tq][cq4+3]=h2f(e4s.w);
      ushort4 k4 = *(const ushort4*)&((const unsigned short*)kbuf)[gi];
      ushort4 r4 = *(const ushort4*)&((const unsigned short*)rbuf)[gi];
      float q0=bfbits(k4.x),q1=bfbits(k4.y),q2=bfbits(k4.z),q3=bfbits(k4.w);
      float rv0=bfbits(r4.x),rv1=bfbits(r4.y),rv2=bfbits(r4.z),rv3=bfbits(r4.w);
      qk[tq][cq4+0]=q0; qk[tq][cq4+1]=q1; qk[tq][cq4+2]=q2; qk[tq][cq4+3]=q3;
      rr[tq][cq4+0]=rv0; rr[tq][cq4+1]=rv1; rr[tq][cq4+2]=rv2; rr[tq][cq4+3]=rv3;
      float part = rv0*q0*u4.x + rv1*q1*u4.y + rv2*q2*u4.z + rv3*q3*u4.w;
      part += __shfl_xor(part,1,64); part += __shfl_xor(part,2,64);
      part += __shfl_xor(part,4,64); part += __shfl_xor(part,8,64);
      if ((tid&15)==0) bu[tq] = part;
      *(u16x8*)&vtb[tq][cq8] = *(const u16x8*)&((const unsigned short*)vbuf)[((size_t)b*TT + tb + tq)*VD + h*128 + cq8];
    }
    __syncthreads();
    #pragma unroll 1
    for (int t=0;t<8;t++){
      float vl = bfbits(vtb[t][tid]);
      f32x2 vl2 = {vl, vl};
      f32x2 o2 = {0.f, 0.f};
      #pragma unroll
      for (int g=0;g<16;g++){
        f32x4 e4 = *(const f32x4*)&ew[t][g*4];
        f32x4 q4 = *(const f32x4*)&qk[t][g*4];
        f32x4 r4 = *(const f32x4*)&rr[t][g*4];
        f32x2 eA = {e4[0],e4[1]}, eB = {e4[2],e4[3]};
        f32x2 qA = {q4[0],q4[1]}, qB = {q4[2],q4[3]};
        f32x2 rA = {r4[0],r4[1]}, rB = {r4[2],r4[3]};
        int p = g*2;
        o2 += rA*S2[p];   S2[p]   = eA*S2[p]   + qA*vl2;
        o2 += rB*S2[p+1]; S2[p+1] = eB*S2[p+1] + qB*vl2;
      }
      float o = o2[0] + o2[1] + bu[t]*vl;
      ot[t][tid] = o;
    }
    __syncthreads();
    {
      float gw[8], gb[8];
      *(float4*)&gw[0] = *(const float4*)&gn_w[h*128+cq8];
      *(float4*)&gw[4] = *(const float4*)&gn_w[h*128+cq8+4];
      *(float4*)&gb[0] = *(const float4*)&gn_b[h*128+cq8];
      *(float4*)&gb[4] = *(const float4*)&gn_b[h*128+cq8+4];
      float o8[8];
      *(float4*)&o8[0] = *(const float4*)&ot[tq][cq8];
      *(float4*)&o8[4] = *(const float4*)&ot[tq][cq8+4];
      float s = 0.f, ss = 0.f;
      #pragma unroll
      for (int e=0;e<8;e++){ s += o8[e]; ss += o8[e]*o8[e]; }
      s += __shfl_xor(s,1,64); ss += __shfl_xor(ss,1,64);
      s += __shfl_xor(s,2,64); ss += __shfl_xor(ss,2,64);
      s += __shfl_xor(s,4,64); ss += __shfl_xor(ss,4,64);
      s += __shfl_xor(s,8,64); ss += __shfl_xor(ss,8,64);
      float mu = s*(1.f/128.f);
      float inv = rsqrtf(fmaxf(ss*(1.f/128.f) - mu*mu, 0.f) + 1e-5f);
      size_t go = ((size_t)b*TT + tb + tq)*VD + h*128 + cq8;
      u16x8 g8 = *(const u16x8*)&((const unsigned short*)gg)[go];
      u16x8 out8;
      #pragma unroll
      for (int e=0;e<8;e++){
        float xv = (o8[e]-mu)*inv*gw[e] + gb[e];
        float ga = bfbits(g8[e]);
        xv *= ga/(1.f+expf(-ga));
        out8[e] = f2bfbits(xv);
      }
      *(u16x8*)&((unsigned short*)gated)[go] = out8;
    }
    __syncthreads();
  }
}

// ---------------- FFN lerp inputs (bf16, 8 elems/thread) ----------------
__global__ void build_ffn_in(const bf16* __restrict__ hn, const float* __restrict__ mu_k,
                             const float* __restrict__ mu_r, bf16* __restrict__ kin, bf16* __restrict__ rin){
  size_t base = ((size_t)blockIdx.x*256 + threadIdx.x)*8;
  int c = (int)(base & (CC-1));
  size_t bt = base >> 9;
  u16x8 hv8 = *(const u16x8*)&((const unsigned short*)hn)[base];
  u16x8 hp8;
  if (bt & (TT-1)) hp8 = *(const u16x8*)&((const unsigned short*)hn)[base - CC];
  else { hp8 = u16x8{0,0,0,0,0,0,0,0}; }
  float mk8[8], mr8[8];
  *(float4*)&mk8[0] = *(const float4*)&mu_k[c];
  *(float4*)&mk8[4] = *(const float4*)&mu_k[c+4];
  *(float4*)&mr8[0] = *(const float4*)&mu_r[c];
  *(float4*)&mr8[4] = *(const float4*)&mu_r[c+4];
  u16x8 k8, r8;
  #pragma unroll
  for (int e=0;e<8;e++){
    float f = bfbits(hv8[e]), p = bfbits(hp8[e]);
    float d = p - f;
    k8[e] = f2bfbits(f + d*mk8[e]);
    r8[e] = f2bfbits(f + d*mr8[e]);
  }
  *(u16x8*)&((unsigned short*)kin)[base] = k8;
  *(u16x8*)&((unsigned short*)rin)[base] = r8;
}

extern "C" void kernel_launch(void* const* d_in, const int* in_sizes, int n_in,
                              void* d_out, int out_size, void* d_ws, size_t ws_size,
                              hipStream_t stream){
  (void)in_sizes; (void)n_in; (void)out_size;
  if (ws_size < WS_NEED) return;
  const float* x      = (const float*)d_in[0];
  const float* ln1w   = (const float*)d_in[1];
  const float* ln1b   = (const float*)d_in[2];
  const float* mu_x   = (const float*)d_in[3];
  const float* W_x1   = (const float*)d_in[4];
  const float* W_x2   = (const float*)d_in[5];
  const float* x_bias = (const float*)d_in[6];
  const float* W_r    = (const float*)d_in[7];
  const float* W_k    = (const float*)d_in[8];
  const float* W_v    = (const float*)d_in[9];
  const float* W_g    = (const float*)d_in[10];
  const float* W_w1   = (const float*)d_in[11];
  const float* W_w2   = (const float*)d_in[12];
  const float* b_w2   = (const float*)d_in[13];
  const float* u      = (const float*)d_in[14];
  const float* gn_w   = (const float*)d_in[15];
  const float* gn_b   = (const float*)d_in[16];
  const float* W_o    = (const float*)d_in[17];
  const float* ln2w   = (const float*)d_in[18];
  const float* ln2b   = (const float*)d_in[19];
  const float* mu_k   = (const float*)d_in[20];
  const float* W_key  = (const float*)d_in[21];
  const float* mu_r   = (const float*)d_in[22];
  const float* W_rec  = (const float*)d_in[23];
  const float* W_val  = (const float*)d_in[24];
  char* ws = (char*)d_ws;
  auto F  = [&](size_t off){ return (float*)(ws+off); };
  auto Bf = [&](size_t off){ return (bf16*)(ws+off); };
  float* h2 = (float*)d_out;        // attn-out residual lives in d_out
  bf16* Mseg = (bf16*)d_out;        // scan summaries alias d_out (dead before O-gemm)

  // weight conversions
  wconv_t2<<<620,256,0,stream>>>(W_x1,W_r,W_k,W_v,W_g,W_w1,W_w2,W_o,W_key,W_rec,W_val, ws);
  wconv_x2<<<320,256,0,stream>>>(W_x2, Bf(WT_X2T));

  // ---- attention pre-projections ----
  ln_bf16<<<BT,256,0,stream>>>(x, ln1w, ln1b, Bf(OFF_H1));
  build_xm<<<BT*CC/8/256,256,0,stream>>>(Bf(OFF_H1), mu_x, Bf(OFF_HM));
  gemm128<EP_TANH_BF16><<<512,256,0,stream>>>(Bf(OFF_HM), Bf(WT_X1), Bf(OFF_XX), 256,512, nullptr,nullptr);

  // MFMA-fused 5-way hm build: hm0->HM, hm1->dout[0:32M], hm2->dout[32M:64M], hm3->G region, hm4->WD region
  bf16* hm1 = (bf16*)d_out;
  bf16* hm2 = (bf16*)((char*)d_out + 32*MiB);
  hm5_mfma<<<dim3(BT/128,4),256,0,stream>>>(Bf(OFF_H1), Bf(OFF_XX), Bf(WT_X2T), x_bias,
                                            Bf(OFF_HM), hm1, hm2, Bf(OFF_G), Bf(OFF_WD));
  // projections (order keeps region lifetimes disjoint)
  gemm128<EP_BF16><<<512,256,0,stream>>>(Bf(OFF_HM), Bf(WT_R), Bf(OFF_R), 256,512, nullptr,nullptr);
  gemm_bf16<EP_TANH_BF16><<<dim3(BT/128,1),256,0,stream>>>(hm1, Bf(WT_W1), Bf(OFF_W1T), 64,512, nullptr);
  gemm128<EP_BF16><<<512,256,0,stream>>>(hm2, Bf(WT_K), Bf(OFF_K), 256,512, nullptr,nullptr);
  gemm128<EP_BF16><<<1024,256,0,stream>>>(Bf(OFF_G), Bf(WT_V), Bf(OFF_V), 512,512, nullptr,nullptr);
  gemm128<EP_BF16><<<1024,256,0,stream>>>(Bf(OFF_WD), Bf(WT_G), Bf(OFF_G), 512,512, nullptr,nullptr);
  gemm_bf16<EP_NEGEXP_F16><<<dim3(BT/128,4),256,0,stream>>>(Bf(OFF_W1T), Bf(WT_W2), (void*)F(OFF_WD), 256,64, b_w2);

  // ---- WKV6 segment scan (SUB=64, NSUB=64); Mseg/Sstart in d_out ----
  wkv_p1<<<BB*4*NSUB,128,0,stream>>>(Bf(OFF_K), Bf(OFF_V), (const f16*)F(OFF_WD), Mseg, F(OFF_DSEG));
  wkv_p2<<<BB*4*8192/256,256,0,stream>>>(Mseg, F(OFF_DSEG));
  wkv_p3<<<BB*4*NSUB,128,0,stream>>>(Bf(OFF_R), Bf(OFF_K), Bf(OFF_V), (const f16*)F(OFF_WD), Mseg, u,
                                     Bf(OFF_G), gn_w, gn_b, Bf(OFF_H1));

  // ---- output projection + residual -> h2 (in d_out; overwrites Mseg) ----
  gemm128<EP_RES_F32><<<1024,256,0,stream>>>(Bf(OFF_H1), Bf(WT_O), h2, 512,512, x,nullptr);

  // ---- channel mixing (FFN) ----
  ln_bf16<<<BT,256,0,stream>>>(h2, ln2w, ln2b, Bf(OFF_HM));
  build_ffn_in<<<BT*CC/8/256,256,0,stream>>>(Bf(OFF_HM), mu_k, mu_r, Bf(OFF_R), Bf(OFF_V));
  gemm128<EP_RELU2_BF16><<<2048,256,0,stream>>>(Bf(OFF_R), Bf(WT_KEY), Bf(OFF_WD), 1024,512, nullptr,nullptr);
  gemm128<EP_SIG_BF16><<<1024,256,0,stream>>>(Bf(OFF_V), Bf(WT_REC), Bf(OFF_H1), 512,512, nullptr,nullptr);
  gemm128<EP_FINAL_F32><<<1024,256,0,stream>>>(Bf(OFF_WD), Bf(WT_VAL), h2, 512,1024, h2, Bf(OFF_H1));
}